// Round 3
// baseline (577.718 us; speedup 1.0000x reference)
//
#include <hip/hip_runtime.h>
#include <math.h>

// Shapes (static): B=4, D=64, Wd=Hd=48 -> N=2304, heads=4, dh=16, scalar=4.
// All reference .view()/.reshape() quirks are flat-buffer reinterprets:
//   x_flat[b,d,n] = x[b*147456 + d*2304 + n]
//   x_r[b,n,d]    = x[b*147456 + n*64 + d]
//   f_img[d,n]    = f2flat[d*2304 + n]   (f2flat written as [n*64+e])
//   outs[h][r,c]  = vflat[r*16+c]        (vflat written as [k*2304+n'])
//   cat_img[d,n]  = catflat[d*2304+n]    (catflat written as [r*64+h*16+c])

#define OFF_A   0          // 4*64*64 = 16384 floats
#define OFF_SC  16384      // 1 float (gamma/bound)
#define OFF_QT  17408      // [bh=16][k=16][n=2304] = 589824
#define OFF_QN  607232     // [bh=16][n=2304] = 36864
#define OFF_F2  644096     // [bh=16][n*64+e] = 2359296
#define OFF_CAT 3003392    // [b=4][147456] = 589824
// total 3593216 floats = 14.4 MB of d_ws

__global__ __launch_bounds__(256) void k_setup(
    const float* __restrict__ Wq, const float* __restrict__ Wv,
    const float* __restrict__ Wo, const float* __restrict__ gamma, float* ws)
{
    __shared__ double red[256];
    __shared__ double sums[9];   // |Wq_h|^2 x4, |Wv_h|^2 x4, |Wo|^2
    int t = threadIdx.x;
    for (int ph = 0; ph < 9; ++ph) {
        double s = 0.0;
        if (ph < 4) {
            const float* W = Wq + ph * 1024;
            for (int i = t; i < 1024; i += 256) { double v = W[i]; s += v * v; }
        } else if (ph < 8) {
            const float* W = Wv + (ph - 4) * 1024;
            for (int i = t; i < 1024; i += 256) { double v = W[i]; s += v * v; }
        } else {
            for (int i = t; i < 4096; i += 256) { double v = Wo[i]; s += v * v; }
        }
        red[t] = s; __syncthreads();
        for (int off = 128; off; off >>= 1) {
            if (t < off) red[t] += red[t + off];
            __syncthreads();
        }
        if (t == 0) sums[ph] = red[0];
        __syncthreads();
    }
    if (t == 0) {
        // W0(N/e) Newton, matching the numpy float64 iteration
        double z = 2304.0 / 2.71828182845904523536;
        double w = log(z) - log(log(z));
        for (int it = 0; it < 30; ++it) {
            double ew = exp(w);
            w = w - (w * ew - z) / (ew * (w + 1.0));
        }
        double phi = (double)(float)w;  // reference casts to f32
        double term = sqrt(sums[0]*sums[4] + sums[1]*sums[5] +
                           sums[2]*sums[6] + sums[3]*sums[7]);
        double bound = 6.0 * (4.0 * phi + 1.0) * term * sqrt(sums[8]);
        ws[OFF_SC] = (float)((double)gamma[0] / bound);
    }
    // A[h] = WqR @ WqR^T / 4 ; WqR[d,k] = Wqflat[h*1024 + d*16 + k]
    for (int idx = t; idx < 16384; idx += 256) {
        int h = idx >> 12, r = idx & 4095, d = r >> 6, e = r & 63;
        const float* W = Wq + h * 1024;
        float s = 0.f;
        #pragma unroll
        for (int k = 0; k < 16; ++k) s += W[d * 16 + k] * W[e * 16 + k];
        ws[OFF_A + idx] = s * 0.25f;
    }
}

// q[b,h,n,k] = sum_d Wq[h,k,d] * x_flat[b,d,n] + bq[h,k]; store k-major + qn
__global__ __launch_bounds__(256) void k_q(
    const float* __restrict__ x, const float* __restrict__ Wq,
    const float* __restrict__ bq, float* ws)
{
    __shared__ float Wl[1024];
    __shared__ float bl[16];
    int bid = blockIdx.x, bh = bid / 9, nt = bid % 9;
    int h = bh & 3, b = bh >> 2, t = threadIdx.x;
    for (int i = t; i < 1024; i += 256) Wl[i] = Wq[h * 1024 + i];
    if (t < 16) bl[t] = bq[h * 16 + t];
    __syncthreads();
    int n = nt * 256 + t;
    const float* xb = x + b * 147456;
    float q[16];
    #pragma unroll
    for (int k = 0; k < 16; ++k) q[k] = bl[k];
    for (int d = 0; d < 64; ++d) {
        float xv = xb[d * 2304 + n];
        #pragma unroll
        for (int k = 0; k < 16; ++k) q[k] = fmaf(Wl[k * 64 + d], xv, q[k]);
    }
    float qn = 0.f;
    #pragma unroll
    for (int k = 0; k < 16; ++k) {
        ws[OFF_QT + (bh * 16 + k) * 2304 + n] = q[k];
        qn = fmaf(q[k], q[k], qn);
    }
    ws[OFF_QN + bh * 2304 + n] = qn;
}

// Flash attention with L2 distance logits + f@A epilogue.
// Block: 128 rows of one (b,h). Thread (tg=t>>3, sub=t&7): rows tg+32i, d's sub*8..+7.
__global__ __launch_bounds__(256, 2) void k_attn(const float* __restrict__ x, float* ws)
{
    __shared__ __align__(16) float qtT[64 * 20];   // [m][k], pitch 20
    __shared__ float qnm[64];
    __shared__ __align__(16) float xr[64 * 68];    // [m][d], pitch 68
    __shared__ __align__(16) float pls[128 * 68];  // [row][m] probs, pitch 68
    int bid = blockIdx.x, bh = bid / 18, rt = bid % 18;
    int h = bh & 3, b = bh >> 2;
    int n0 = rt * 128, t = threadIdx.x;
    int sub = t & 7, tg = t >> 3;
    const float* qt_g = ws + OFF_QT + bh * 16 * 2304;
    const float* qn_g = ws + OFF_QN + bh * 2304;
    const float* xb = x + b * 147456;

    float qreg[4][16], qnr[4];
    #pragma unroll
    for (int i = 0; i < 4; ++i) {
        int n = n0 + tg + 32 * i;
        qnr[i] = qn_g[n];
        #pragma unroll
        for (int k = 0; k < 16; ++k) qreg[i][k] = qt_g[k * 2304 + n];
    }
    float facc[4][8];
    #pragma unroll
    for (int i = 0; i < 4; ++i)
        #pragma unroll
        for (int j = 0; j < 8; ++j) facc[i][j] = 0.f;
    float mrun[4] = {-INFINITY, -INFINITY, -INFINITY, -INFINITY};
    float lrun[4] = {0.f, 0.f, 0.f, 0.f};

    for (int mt = 0; mt < 36; ++mt) {
        int m0 = mt * 64;
        for (int idx = t; idx < 1024; idx += 256) {
            int k = idx >> 6, mm = idx & 63;
            qtT[mm * 20 + k] = qt_g[k * 2304 + m0 + mm];
        }
        if (t < 64) qnm[t] = qn_g[m0 + t];
        for (int idx = t; idx < 4096; idx += 256) {
            int mm = idx >> 6, d = idx & 63;
            xr[mm * 68 + d] = xb[(m0 + mm) * 64 + d];
        }
        __syncthreads();

        float pl[4][8];
        #pragma unroll
        for (int mi = 0; mi < 8; ++mi) {
            int m = sub + 8 * mi;
            float4 a0 = *(const float4*)(qtT + m * 20 + 0);
            float4 a1 = *(const float4*)(qtT + m * 20 + 4);
            float4 a2 = *(const float4*)(qtT + m * 20 + 8);
            float4 a3 = *(const float4*)(qtT + m * 20 + 12);
            float qm = qnm[m];
            #pragma unroll
            for (int i = 0; i < 4; ++i) {
                float s = qreg[i][0]*a0.x + qreg[i][1]*a0.y + qreg[i][2]*a0.z + qreg[i][3]*a0.w
                        + qreg[i][4]*a1.x + qreg[i][5]*a1.y + qreg[i][6]*a1.z + qreg[i][7]*a1.w
                        + qreg[i][8]*a2.x + qreg[i][9]*a2.y + qreg[i][10]*a2.z + qreg[i][11]*a2.w
                        + qreg[i][12]*a3.x + qreg[i][13]*a3.y + qreg[i][14]*a3.z + qreg[i][15]*a3.w;
                float dist = qnr[i] + qm - 2.f * s;
                pl[i][mi] = -0.25f * dist;
            }
        }
        #pragma unroll
        for (int i = 0; i < 4; ++i) {
            float tm = pl[i][0];
            #pragma unroll
            for (int mi = 1; mi < 8; ++mi) tm = fmaxf(tm, pl[i][mi]);
            tm = fmaxf(tm, __shfl_xor(tm, 1, 8));
            tm = fmaxf(tm, __shfl_xor(tm, 2, 8));
            tm = fmaxf(tm, __shfl_xor(tm, 4, 8));
            float mnew = fmaxf(mrun[i], tm);
            float fac = __expf(mrun[i] - mnew);
            lrun[i] *= fac;
            #pragma unroll
            for (int j = 0; j < 8; ++j) facc[i][j] *= fac;
            float ps = 0.f;
            int lr = tg + 32 * i;
            #pragma unroll
            for (int mi = 0; mi < 8; ++mi) {
                float pv = __expf(pl[i][mi] - mnew);
                ps += pv;
                pls[lr * 68 + sub + 8 * mi] = pv;
            }
            lrun[i] += ps;
            mrun[i] = mnew;
        }
        __syncthreads();

        for (int mc = 0; mc < 16; ++mc) {
            int mb = mc * 4;
            float4 pp0 = *(const float4*)(pls + (tg +  0) * 68 + mb);
            float4 pp1 = *(const float4*)(pls + (tg + 32) * 68 + mb);
            float4 pp2 = *(const float4*)(pls + (tg + 64) * 68 + mb);
            float4 pp3 = *(const float4*)(pls + (tg + 96) * 68 + mb);
            float pr0[4] = {pp0.x, pp0.y, pp0.z, pp0.w};
            float pr1[4] = {pp1.x, pp1.y, pp1.z, pp1.w};
            float pr2[4] = {pp2.x, pp2.y, pp2.z, pp2.w};
            float pr3[4] = {pp3.x, pp3.y, pp3.z, pp3.w};
            #pragma unroll
            for (int mi = 0; mi < 4; ++mi) {
                const float* xp = xr + (mb + mi) * 68 + sub * 8;
                float4 xa = *(const float4*)(xp);
                float4 xc = *(const float4*)(xp + 4);
                float p0 = pr0[mi], p1 = pr1[mi], p2 = pr2[mi], p3 = pr3[mi];
                facc[0][0]=fmaf(p0,xa.x,facc[0][0]); facc[0][1]=fmaf(p0,xa.y,facc[0][1]);
                facc[0][2]=fmaf(p0,xa.z,facc[0][2]); facc[0][3]=fmaf(p0,xa.w,facc[0][3]);
                facc[0][4]=fmaf(p0,xc.x,facc[0][4]); facc[0][5]=fmaf(p0,xc.y,facc[0][5]);
                facc[0][6]=fmaf(p0,xc.z,facc[0][6]); facc[0][7]=fmaf(p0,xc.w,facc[0][7]);
                facc[1][0]=fmaf(p1,xa.x,facc[1][0]); facc[1][1]=fmaf(p1,xa.y,facc[1][1]);
                facc[1][2]=fmaf(p1,xa.z,facc[1][2]); facc[1][3]=fmaf(p1,xa.w,facc[1][3]);
                facc[1][4]=fmaf(p1,xc.x,facc[1][4]); facc[1][5]=fmaf(p1,xc.y,facc[1][5]);
                facc[1][6]=fmaf(p1,xc.z,facc[1][6]); facc[1][7]=fmaf(p1,xc.w,facc[1][7]);
                facc[2][0]=fmaf(p2,xa.x,facc[2][0]); facc[2][1]=fmaf(p2,xa.y,facc[2][1]);
                facc[2][2]=fmaf(p2,xa.z,facc[2][2]); facc[2][3]=fmaf(p2,xa.w,facc[2][3]);
                facc[2][4]=fmaf(p2,xc.x,facc[2][4]); facc[2][5]=fmaf(p2,xc.y,facc[2][5]);
                facc[2][6]=fmaf(p2,xc.z,facc[2][6]); facc[2][7]=fmaf(p2,xc.w,facc[2][7]);
                facc[3][0]=fmaf(p3,xa.x,facc[3][0]); facc[3][1]=fmaf(p3,xa.y,facc[3][1]);
                facc[3][2]=fmaf(p3,xa.z,facc[3][2]); facc[3][3]=fmaf(p3,xa.w,facc[3][3]);
                facc[3][4]=fmaf(p3,xc.x,facc[3][4]); facc[3][5]=fmaf(p3,xc.y,facc[3][5]);
                facc[3][6]=fmaf(p3,xc.z,facc[3][6]); facc[3][7]=fmaf(p3,xc.w,facc[3][7]);
            }
        }
        __syncthreads();
    }

    float inv[4];
    #pragma unroll
    for (int i = 0; i < 4; ++i) {
        float L = lrun[i];
        L += __shfl_xor(L, 1, 8);
        L += __shfl_xor(L, 2, 8);
        L += __shfl_xor(L, 4, 8);
        inv[i] = 1.f / L;
    }
    #pragma unroll
    for (int i = 0; i < 4; ++i) {
        int lr = tg + 32 * i;
        #pragma unroll
        for (int j = 0; j < 8; ++j) pls[lr * 68 + sub * 8 + j] = facc[i][j] * inv[i];
    }
    __syncthreads();
    // f2 = f @ A
    const float* Ag = ws + OFF_A + h * 4096;
    float f2[4][8];
    #pragma unroll
    for (int i = 0; i < 4; ++i)
        #pragma unroll
        for (int j = 0; j < 8; ++j) f2[i][j] = 0.f;
    for (int d4 = 0; d4 < 16; ++d4) {
        float4 fd0 = *(const float4*)(pls + (tg +  0) * 68 + d4 * 4);
        float4 fd1 = *(const float4*)(pls + (tg + 32) * 68 + d4 * 4);
        float4 fd2 = *(const float4*)(pls + (tg + 64) * 68 + d4 * 4);
        float4 fd3 = *(const float4*)(pls + (tg + 96) * 68 + d4 * 4);
        float fr0[4] = {fd0.x, fd0.y, fd0.z, fd0.w};
        float fr1[4] = {fd1.x, fd1.y, fd1.z, fd1.w};
        float fr2[4] = {fd2.x, fd2.y, fd2.z, fd2.w};
        float fr3[4] = {fd3.x, fd3.y, fd3.z, fd3.w};
        #pragma unroll
        for (int dd = 0; dd < 4; ++dd) {
            int d = d4 * 4 + dd;
            float4 a4 = *(const float4*)(Ag + d * 64 + sub * 8);
            float4 b4 = *(const float4*)(Ag + d * 64 + sub * 8 + 4);
            float f0 = fr0[dd], f1 = fr1[dd], f2v = fr2[dd], f3 = fr3[dd];
            f2[0][0]=fmaf(f0,a4.x,f2[0][0]); f2[0][1]=fmaf(f0,a4.y,f2[0][1]);
            f2[0][2]=fmaf(f0,a4.z,f2[0][2]); f2[0][3]=fmaf(f0,a4.w,f2[0][3]);
            f2[0][4]=fmaf(f0,b4.x,f2[0][4]); f2[0][5]=fmaf(f0,b4.y,f2[0][5]);
            f2[0][6]=fmaf(f0,b4.z,f2[0][6]); f2[0][7]=fmaf(f0,b4.w,f2[0][7]);
            f2[1][0]=fmaf(f1,a4.x,f2[1][0]); f2[1][1]=fmaf(f1,a4.y,f2[1][1]);
            f2[1][2]=fmaf(f1,a4.z,f2[1][2]); f2[1][3]=fmaf(f1,a4.w,f2[1][3]);
            f2[1][4]=fmaf(f1,b4.x,f2[1][4]); f2[1][5]=fmaf(f1,b4.y,f2[1][5]);
            f2[1][6]=fmaf(f1,b4.z,f2[1][6]); f2[1][7]=fmaf(f1,b4.w,f2[1][7]);
            f2[2][0]=fmaf(f2v,a4.x,f2[2][0]); f2[2][1]=fmaf(f2v,a4.y,f2[2][1]);
            f2[2][2]=fmaf(f2v,a4.z,f2[2][2]); f2[2][3]=fmaf(f2v,a4.w,f2[2][3]);
            f2[2][4]=fmaf(f2v,b4.x,f2[2][4]); f2[2][5]=fmaf(f2v,b4.y,f2[2][5]);
            f2[2][6]=fmaf(f2v,b4.z,f2[2][6]); f2[2][7]=fmaf(f2v,b4.w,f2[2][7]);
            f2[3][0]=fmaf(f3,a4.x,f2[3][0]); f2[3][1]=fmaf(f3,a4.y,f2[3][1]);
            f2[3][2]=fmaf(f3,a4.z,f2[3][2]); f2[3][3]=fmaf(f3,a4.w,f2[3][3]);
            f2[3][4]=fmaf(f3,b4.x,f2[3][4]); f2[3][5]=fmaf(f3,b4.y,f2[3][5]);
            f2[3][6]=fmaf(f3,b4.z,f2[3][6]); f2[3][7]=fmaf(f3,b4.w,f2[3][7]);
        }
    }
    float* f2g = ws + OFF_F2 + bh * 147456;
    #pragma unroll
    for (int i = 0; i < 4; ++i) {
        int n = n0 + tg + 32 * i;
        #pragma unroll
        for (int j = 0; j < 8; ++j) f2g[n * 64 + sub * 8 + j] = f2[i][j];
    }
}

// v = Wv*f_img + bv, scattered into cat via the [N,dh] reinterpret
__global__ __launch_bounds__(256) void k_v(
    const float* __restrict__ Wv, const float* __restrict__ bv, float* ws)
{
    __shared__ float Wl[1024];
    __shared__ float bl[16];
    int bid = blockIdx.x, bh = bid / 9, nt = bid % 9;
    int h = bh & 3, b = bh >> 2, t = threadIdx.x;
    for (int i = t; i < 1024; i += 256) Wl[i] = Wv[h * 1024 + i];
    if (t < 16) bl[t] = bv[h * 16 + t];
    __syncthreads();
    int n = nt * 256 + t;
    const float* f2g = ws + OFF_F2 + bh * 147456;
    float v[16];
    #pragma unroll
    for (int k = 0; k < 16; ++k) v[k] = bl[k];
    for (int d = 0; d < 64; ++d) {
        float fv = f2g[d * 2304 + n];
        #pragma unroll
        for (int k = 0; k < 16; ++k) v[k] = fmaf(Wl[k * 64 + d], fv, v[k]);
    }
    float* cat = ws + OFF_CAT + b * 147456;
    #pragma unroll
    for (int k = 0; k < 16; ++k) {
        int j = k * 2304 + n;
        cat[(j >> 4) * 64 + h * 16 + (j & 15)] = v[k];
    }
}

// out = sc*(Wo@cat_img + bo) + x
__global__ __launch_bounds__(256) void k_out(
    const float* __restrict__ x, const float* __restrict__ Wo,
    const float* __restrict__ bo, const float* ws, float* __restrict__ out)
{
    __shared__ float Wl[1024];   // WoT slice [d][oo]
    __shared__ float bl[16];
    __shared__ float scs;
    int bid = blockIdx.x;
    int b = bid / 36, rem = bid % 36, nt = rem / 4, og = rem % 4;
    int t = threadIdx.x;
    for (int idx = t; idx < 1024; idx += 256) {
        int d = idx >> 4, oo = idx & 15;
        Wl[idx] = Wo[(og * 16 + oo) * 64 + d];
    }
    if (t < 16) bl[t] = bo[og * 16 + t];
    if (t == 0) scs = ws[OFF_SC];
    __syncthreads();
    int n = nt * 256 + t;
    const float* cat = ws + OFF_CAT + b * 147456;
    float acc[16];
    #pragma unroll
    for (int oo = 0; oo < 16; ++oo) acc[oo] = bl[oo];
    for (int d = 0; d < 64; ++d) {
        float cv = cat[d * 2304 + n];
        #pragma unroll
        for (int oo = 0; oo < 16; ++oo) acc[oo] = fmaf(Wl[d * 16 + oo], cv, acc[oo]);
    }
    float sc = scs;
    const float* xb = x + b * 147456;
    float* ob = out + b * 147456;
    #pragma unroll
    for (int oo = 0; oo < 16; ++oo) {
        int o = og * 16 + oo;
        ob[o * 2304 + n] = fmaf(sc, acc[oo], xb[o * 2304 + n]);
    }
}

extern "C" void kernel_launch(void* const* d_in, const int* in_sizes, int n_in,
                              void* d_out, int out_size, void* d_ws, size_t ws_size,
                              hipStream_t stream) {
    const float* x     = (const float*)d_in[0];
    const float* Wq    = (const float*)d_in[1];
    const float* bq    = (const float*)d_in[2];
    const float* Wv    = (const float*)d_in[3];
    const float* bv    = (const float*)d_in[4];
    const float* Wo    = (const float*)d_in[5];
    const float* bo    = (const float*)d_in[6];
    const float* gamma = (const float*)d_in[7];
    float* out = (float*)d_out;
    float* ws  = (float*)d_ws;
    k_setup<<<1,   256, 0, stream>>>(Wq, Wv, Wo, gamma, ws);
    k_q    <<<144, 256, 0, stream>>>(x, Wq, bq, ws);
    k_attn <<<288, 256, 0, stream>>>(x, ws);
    k_v    <<<144, 256, 0, stream>>>(Wv, bv, ws);
    k_out  <<<144, 256, 0, stream>>>(x, Wo, bo, ws, out);
}

// Round 4
// 198.897 us; speedup vs baseline: 2.9046x; 2.9046x over previous
//
#include <hip/hip_runtime.h>
#include <math.h>

// B=4, D=64, Wd=Hd=48 -> N=2304, heads=4, dh=16, scalar=4.
// Attention branch is divided by bound~2100 => bf16 MFMA precision is ample.
// ws layout (floats):
#define OFF_SC  0          // 1 float (gamma/bound)
#define OFF_AF  16         // A-matrix bf16 frag layout [4h][4t][2ec][64][8] = 16384 bf16 = 8192 f
#define OFF_QF  8208       // Q bf16 frag layout [16bh][72rc][64][8] = 589824 bf16 = 294912 f
#define OFF_QN  303120     // -0.5*|q|^2 f32 [16bh][2304] = 36864 f
#define OFF_XF  339984     // x_r bf16 frag layout [4b][144T][2dc][64][8] = 294912 f
#define OFF_F2  634896     // f2 f32 [16bh][147456] = 2359296 f
#define OFF_CAT 2994192    // [4b][147456] = 589824 f
// total 3584016 floats = 13.7 MB

typedef __attribute__((ext_vector_type(8))) short bf16x8;
typedef __attribute__((ext_vector_type(16))) float f32x16;
union U4 { uint4 u; bf16x8 b; };

__device__ __forceinline__ unsigned short f2bf(float x) {
    unsigned int u = __float_as_uint(x);
    unsigned int r = u + 0x7fffu + ((u >> 16) & 1u);
    return (unsigned short)(r >> 16);
}

__global__ __launch_bounds__(256) void k_setup(
    const float* __restrict__ Wq, const float* __restrict__ Wv,
    const float* __restrict__ Wo, const float* __restrict__ gamma, float* ws)
{
    __shared__ double red[256];
    __shared__ double sums[9];
    int t = threadIdx.x;
    for (int ph = 0; ph < 9; ++ph) {
        double s = 0.0;
        if (ph < 4) {
            const float* W = Wq + ph * 1024;
            for (int i = t; i < 1024; i += 256) { double v = W[i]; s += v * v; }
        } else if (ph < 8) {
            const float* W = Wv + (ph - 4) * 1024;
            for (int i = t; i < 1024; i += 256) { double v = W[i]; s += v * v; }
        } else {
            for (int i = t; i < 4096; i += 256) { double v = Wo[i]; s += v * v; }
        }
        red[t] = s; __syncthreads();
        for (int off = 128; off; off >>= 1) {
            if (t < off) red[t] += red[t + off];
            __syncthreads();
        }
        if (t == 0) sums[ph] = red[0];
        __syncthreads();
    }
    if (t == 0) {
        double z = 2304.0 / 2.71828182845904523536;
        double w = log(z) - log(log(z));
        for (int it = 0; it < 30; ++it) {
            double ew = exp(w);
            w = w - (w * ew - z) / (ew * (w + 1.0));
        }
        double phi = (double)(float)w;
        double term = sqrt(sums[0]*sums[4] + sums[1]*sums[5] +
                           sums[2]*sums[6] + sums[3]*sums[7]);
        double bound = 6.0 * (4.0 * phi + 1.0) * term * sqrt(sums[8]);
        ws[OFF_SC] = (float)((double)gamma[0] / bound);
    }
    // AF[h][tt][ec][lane][j] = bf16( 0.25 * sum_k Wq[h][d*16+k]*Wq[h][e*16+k] )
    //   d = 16*tt + (lane>>5)*8 + j ; e = ec*32 + (lane&31)
    unsigned short* af = (unsigned short*)(ws + OFF_AF);
    for (int i = t; i < 16384; i += 256) {
        int j = i & 7, l = (i >> 3) & 63, ec = (i >> 9) & 1, tt = (i >> 10) & 3, h = i >> 12;
        int d = 16 * tt + (l >> 5) * 8 + j, e = ec * 32 + (l & 31);
        const float* W = Wq + h * 1024;
        float s = 0.f;
        #pragma unroll
        for (int k = 0; k < 16; ++k) s += W[d * 16 + k] * W[e * 16 + k];
        af[i] = f2bf(0.25f * s);
    }
}

// q = Wq*x_flat + bq. Writes QF (bf16 frag layout) + QN (= -0.5*|q|^2, f32).
__global__ __launch_bounds__(256) void k_q(
    const float* __restrict__ x, const float* __restrict__ Wq,
    const float* __restrict__ bq, float* ws)
{
    __shared__ float Wl[1024];
    __shared__ float bl[16];
    int bid = blockIdx.x, bh = bid / 9, nt = bid % 9;
    int h = bh & 3, b = bh >> 2, t = threadIdx.x;
    for (int i = t; i < 1024; i += 256) Wl[i] = Wq[h * 1024 + i];
    if (t < 16) bl[t] = bq[h * 16 + t];
    __syncthreads();
    int n = nt * 256 + t;
    const float* xb = x + b * 147456;
    float q[16];
    #pragma unroll
    for (int k = 0; k < 16; ++k) q[k] = bl[k];
    for (int d = 0; d < 64; ++d) {
        float xv = xb[d * 2304 + n];
        #pragma unroll
        for (int k = 0; k < 16; ++k) q[k] = fmaf(Wl[k * 64 + d], xv, q[k]);
    }
    float qn = 0.f;
    #pragma unroll
    for (int k = 0; k < 16; ++k) qn = fmaf(q[k], q[k], qn);
    ws[OFF_QN + bh * 2304 + n] = -0.5f * qn;
    unsigned int pk[8];
    #pragma unroll
    for (int i = 0; i < 8; ++i)
        pk[i] = (unsigned int)f2bf(q[2*i]) | ((unsigned int)f2bf(q[2*i+1]) << 16);
    uint4* qf4 = (uint4*)((unsigned short*)(ws + OFF_QF)) + (size_t)(bh * 72 + (n >> 5)) * 64;
    qf4[n & 31]      = make_uint4(pk[0], pk[1], pk[2], pk[3]);
    qf4[32 + (n & 31)] = make_uint4(pk[4], pk[5], pk[6], pk[7]);
}

// XF[b][T][dc][lane][j] = bf16( x_r[b][16T + (lane>>5)*8 + j][dc*32 + (lane&31)] )
__global__ __launch_bounds__(256) void k_xf(const float* __restrict__ x, float* ws)
{
    int i = blockIdx.x * 256 + threadIdx.x;  // 73728 16B-chunks
    int l = i & 63, c1 = i >> 6;
    int dc = c1 & 1, c2 = c1 >> 1;
    int T = c2 % 144, b = c2 / 144;
    const float* xb = x + (size_t)b * 147456;
    int col = dc * 32 + (l & 31), mbase = 16 * T + (l >> 5) * 8;
    unsigned int pk[4];
    #pragma unroll
    for (int jj = 0; jj < 4; ++jj) {
        float f0 = xb[(mbase + 2*jj) * 64 + col];
        float f1 = xb[(mbase + 2*jj + 1) * 64 + col];
        pk[jj] = (unsigned int)f2bf(f0) | ((unsigned int)f2bf(f1) << 16);
    }
    ((uint4*)((unsigned short*)(ws + OFF_XF)))[i] = make_uint4(pk[0], pk[1], pk[2], pk[3]);
}

// Flash attention, MFMA bf16, LDS-free main loop, 4-way m-split per block.
// Block = 32 q-rows of one (b,h); grid = 16*72 = 1152.
__global__ __launch_bounds__(256, 3) void k_attn(float* __restrict__ ws)
{
    __shared__ __align__(16) float Ols[4][32][68];
    __shared__ float Mls[4][32];
    __shared__ float Lls[4][32];
    __shared__ __align__(16) unsigned short fls[32][80];

    const int t = threadIdx.x, w = t >> 6, lane = t & 63;
    const int bid = blockIdx.x, bh = bid / 72, rc = bid % 72;
    const int h = bh & 3, b = bh >> 2;
    const int hi = lane >> 5, nl = lane & 31, s4 = hi * 4;

    const uint4* QF = (const uint4*)((const unsigned short*)(ws + OFF_QF)) + (size_t)bh * 4608;
    const uint4* XF = (const uint4*)((const unsigned short*)(ws + OFF_XF)) + (size_t)b * 18432;
    const float* qn = ws + OFF_QN + bh * 2304;

    U4 qb; qb.u = QF[rc * 64 + lane];   // B-frag: own 32 q-rows, col n = lane&31

    f32x16 O0, O1;
    #pragma unroll
    for (int i = 0; i < 16; ++i) { O0[i] = 0.f; O1[i] = 0.f; }
    float mrun = -INFINITY, lrun = 0.f;

    for (int mt = w; mt < 36; mt += 4) {
        const int m0 = mt * 64;
        U4 xb[8];
        #pragma unroll
        for (int q = 0; q < 8; ++q) xb[q].u = XF[(size_t)(mt * 8 + q) * 64 + lane];
        U4 a0, a1;
        a0.u = QF[(mt * 2) * 64 + lane];
        a1.u = QF[(mt * 2 + 1) * 64 + lane];
        // C-operand carries -0.5*qn_m (row m = (r&3)+8*(r>>2)+4*hi per chunk)
        f32x16 c0, c1;
        #pragma unroll
        for (int g = 0; g < 4; ++g) {
            float4 t4 = *(const float4*)(qn + m0 + 8 * g + s4);
            c0[4*g+0] = t4.x; c0[4*g+1] = t4.y; c0[4*g+2] = t4.z; c0[4*g+3] = t4.w;
            float4 u4 = *(const float4*)(qn + m0 + 32 + 8 * g + s4);
            c1[4*g+0] = u4.x; c1[4*g+1] = u4.y; c1[4*g+2] = u4.z; c1[4*g+3] = u4.w;
        }
        // S^T + qn bias: D[row=m][col=n], logits p = 0.5*(q.q' - 0.5qn... ) => 0.5*s
        f32x16 s0 = __builtin_amdgcn_mfma_f32_32x32x16_bf16(a0.b, qb.b, c0, 0, 0, 0);
        f32x16 s1 = __builtin_amdgcn_mfma_f32_32x32x16_bf16(a1.b, qb.b, c1, 0, 0, 0);
        float p[32];
        #pragma unroll
        for (int r = 0; r < 16; ++r) p[r]      = 0.5f * s0[r];
        #pragma unroll
        for (int r = 0; r < 16; ++r) p[16 + r] = 0.5f * s1[r];
        float tm = p[0];
        #pragma unroll
        for (int r = 1; r < 32; ++r) tm = fmaxf(tm, p[r]);
        tm = fmaxf(tm, __shfl_xor(tm, 32));
        float mnew = fmaxf(mrun, tm);
        float fac = __expf(mrun - mnew);
        float ps = 0.f;
        #pragma unroll
        for (int r = 0; r < 32; ++r) { p[r] = __expf(p[r] - mnew); ps += p[r]; }
        ps += __shfl_xor(ps, 32);
        lrun = fmaf(lrun, fac, ps);
        mrun = mnew;
        // rescale O: redistribute fac from P-layout (n=lane&31) to O-layout (n in regs)
        #pragma unroll
        for (int r = 0; r < 16; ++r) {
            float fo = __shfl(fac, s4 + (r & 3) + 8 * (r >> 2));
            O0[r] *= fo; O1[r] *= fo;
        }
        // P -> bf16 A-frags (cvt_pk + xor32 + half-select), then PV MFMA
        #pragma unroll
        for (int c = 0; c < 2; ++c) {
            unsigned int wd[8], xd[8];
            #pragma unroll
            for (int i = 0; i < 8; ++i)
                asm("v_cvt_pk_bf16_f32 %0, %1, %2"
                    : "=v"(wd[i]) : "v"(p[c*16 + 2*i]), "v"(p[c*16 + 2*i + 1]));
            #pragma unroll
            for (int i = 0; i < 8; ++i) xd[i] = (unsigned int)__shfl_xor((int)wd[i], 32);
            U4 af0, af1;
            af0.u.x = hi ? xd[2] : wd[0];  af0.u.y = hi ? xd[3] : wd[1];
            af0.u.z = hi ? wd[2] : xd[0];  af0.u.w = hi ? wd[3] : xd[1];
            af1.u.x = hi ? xd[6] : wd[4];  af1.u.y = hi ? xd[7] : wd[5];
            af1.u.z = hi ? wd[6] : xd[4];  af1.u.w = hi ? wd[7] : xd[5];
            O0 = __builtin_amdgcn_mfma_f32_32x32x16_bf16(af0.b, xb[4*c+0].b, O0, 0, 0, 0);
            O1 = __builtin_amdgcn_mfma_f32_32x32x16_bf16(af0.b, xb[4*c+1].b, O1, 0, 0, 0);
            O0 = __builtin_amdgcn_mfma_f32_32x32x16_bf16(af1.b, xb[4*c+2].b, O0, 0, 0, 0);
            O1 = __builtin_amdgcn_mfma_f32_32x32x16_bf16(af1.b, xb[4*c+3].b, O1, 0, 0, 0);
        }
    }

    // write partial flash state
    #pragma unroll
    for (int r = 0; r < 16; ++r) {
        int n = (r & 3) + 8 * (r >> 2) + s4;
        Ols[w][n][nl]      = O0[r];
        Ols[w][n][nl + 32] = O1[r];
    }
    if (!hi) { Mls[w][nl] = mrun; Lls[w][nl] = lrun; }
    __syncthreads();

    // combine 4 partials; write f (normalized) as bf16 tile for the f@A mfma
    {
        int n = t >> 3, d0 = (t & 7) * 8;
        float m0v = Mls[0][n], m1v = Mls[1][n], m2v = Mls[2][n], m3v = Mls[3][n];
        float M = fmaxf(fmaxf(m0v, m1v), fmaxf(m2v, m3v));
        float e0 = __expf(m0v - M), e1 = __expf(m1v - M);
        float e2 = __expf(m2v - M), e3 = __expf(m3v - M);
        float L = Lls[0][n]*e0 + Lls[1][n]*e1 + Lls[2][n]*e2 + Lls[3][n]*e3;
        float invL = 1.f / L;
        float f[8];
        #pragma unroll
        for (int d = 0; d < 8; ++d)
            f[d] = (Ols[0][n][d0+d]*e0 + Ols[1][n][d0+d]*e1 +
                    Ols[2][n][d0+d]*e2 + Ols[3][n][d0+d]*e3) * invL;
        unsigned int pk[4];
        #pragma unroll
        for (int i = 0; i < 4; ++i)
            asm("v_cvt_pk_bf16_f32 %0, %1, %2" : "=v"(pk[i]) : "v"(f[2*i]), "v"(f[2*i+1]));
        *(uint4*)((char*)&fls[0][0] + n * 160 + d0 * 2) = make_uint4(pk[0], pk[1], pk[2], pk[3]);
    }
    __syncthreads();

    // f2 = f @ A  (waves 0,1: e-columns ec*32..+31)
    if (w < 2) {
        const int ec = w;
        const uint4* AFp = (const uint4*)((const unsigned short*)(ws + OFF_AF)) + h * 512;
        f32x16 acc;
        #pragma unroll
        for (int i = 0; i < 16; ++i) acc[i] = 0.f;
        #pragma unroll
        for (int tt = 0; tt < 4; ++tt) {
            U4 a, bb;
            a.u  = *(const uint4*)((const char*)&fls[0][0] + nl * 160 + tt * 32 + hi * 16);
            bb.u = AFp[(tt * 2 + ec) * 64 + lane];
            acc = __builtin_amdgcn_mfma_f32_32x32x16_bf16(a.b, bb.b, acc, 0, 0, 0);
        }
        float* f2g = ws + OFF_F2 + (size_t)bh * 147456 + (size_t)rc * 32 * 64;
        #pragma unroll
        for (int r = 0; r < 16; ++r)
            f2g[((r & 3) + 8 * (r >> 2) + s4) * 64 + ec * 32 + nl] = acc[r];
    }
}

// v = Wv*f_img + bv, scattered into cat via the [N,dh] reinterpret
__global__ __launch_bounds__(256) void k_v(
    const float* __restrict__ Wv, const float* __restrict__ bv, float* ws)
{
    __shared__ float Wl[1024];
    __shared__ float bl[16];
    int bid = blockIdx.x, bh = bid / 9, nt = bid % 9;
    int h = bh & 3, b = bh >> 2, t = threadIdx.x;
    for (int i = t; i < 1024; i += 256) Wl[i] = Wv[h * 1024 + i];
    if (t < 16) bl[t] = bv[h * 16 + t];
    __syncthreads();
    int n = nt * 256 + t;
    const float* f2g = ws + OFF_F2 + (size_t)bh * 147456;
    float v[16];
    #pragma unroll
    for (int k = 0; k < 16; ++k) v[k] = bl[k];
    for (int d = 0; d < 64; ++d) {
        float fv = f2g[d * 2304 + n];
        #pragma unroll
        for (int k = 0; k < 16; ++k) v[k] = fmaf(Wl[k * 64 + d], fv, v[k]);
    }
    float* cat = ws + OFF_CAT + (size_t)b * 147456;
    #pragma unroll
    for (int k = 0; k < 16; ++k) {
        int j = k * 2304 + n;
        cat[(j >> 4) * 64 + h * 16 + (j & 15)] = v[k];
    }
}

// out = sc*(Wo@cat_img + bo) + x
__global__ __launch_bounds__(256) void k_out(
    const float* __restrict__ x, const float* __restrict__ Wo,
    const float* __restrict__ bo, const float* ws, float* __restrict__ out)
{
    __shared__ float Wl[1024];
    __shared__ float bl[16];
    __shared__ float scs;
    int bid = blockIdx.x;
    int b = bid / 36, rem = bid % 36, nt = rem / 4, og = rem % 4;
    int t = threadIdx.x;
    for (int idx = t; idx < 1024; idx += 256) {
        int d = idx >> 4, oo = idx & 15;
        Wl[idx] = Wo[(og * 16 + oo) * 64 + d];
    }
    if (t < 16) bl[t] = bo[og * 16 + t];
    if (t == 0) scs = ws[OFF_SC];
    __syncthreads();
    int n = nt * 256 + t;
    const float* cat = ws + OFF_CAT + (size_t)b * 147456;
    float acc[16];
    #pragma unroll
    for (int oo = 0; oo < 16; ++oo) acc[oo] = bl[oo];
    for (int d = 0; d < 64; ++d) {
        float cv = cat[d * 2304 + n];
        #pragma unroll
        for (int oo = 0; oo < 16; ++oo) acc[oo] = fmaf(Wl[d * 16 + oo], cv, acc[oo]);
    }
    float sc = scs;
    const float* xb = x + (size_t)b * 147456;
    float* ob = out + (size_t)b * 147456;
    #pragma unroll
    for (int oo = 0; oo < 16; ++oo) {
        int o = og * 16 + oo;
        ob[o * 2304 + n] = fmaf(sc, acc[oo], xb[o * 2304 + n]);
    }
}

extern "C" void kernel_launch(void* const* d_in, const int* in_sizes, int n_in,
                              void* d_out, int out_size, void* d_ws, size_t ws_size,
                              hipStream_t stream) {
    const float* x     = (const float*)d_in[0];
    const float* Wq    = (const float*)d_in[1];
    const float* bq    = (const float*)d_in[2];
    const float* Wv    = (const float*)d_in[3];
    const float* bv    = (const float*)d_in[4];
    const float* Wo    = (const float*)d_in[5];
    const float* bo    = (const float*)d_in[6];
    const float* gamma = (const float*)d_in[7];
    float* out = (float*)d_out;
    float* ws  = (float*)d_ws;
    k_setup<<<1,    256, 0, stream>>>(Wq, Wv, Wo, gamma, ws);
    k_q    <<<144,  256, 0, stream>>>(x, Wq, bq, ws);
    k_xf   <<<288,  256, 0, stream>>>(x, ws);
    k_attn <<<1152, 256, 0, stream>>>(ws);
    k_v    <<<144,  256, 0, stream>>>(Wv, bv, ws);
    k_out  <<<144,  256, 0, stream>>>(x, Wo, bo, ws, out);
}

// Round 6
// 163.369 us; speedup vs baseline: 3.5363x; 1.2175x over previous
//
#include <hip/hip_runtime.h>
#include <math.h>

// B=4, D=64, N=2304, heads=4, dh=16, scalar=4. Attention output is divided by
// bound~2100 => bf16 everywhere in the attention branch is ample precision.
// Softmax trick: logits = -dist/4 with the FULL shift -0.25*qn_n kept =>
// true row max == 0 exactly (diagonal) => no online-max machinery needed.
// exp2-folding: QFA = bf16(0.5*log2e*q), QFB = bf16(q), QN = -0.25*log2e*|q|^2;
// MFMA(QFA_m,QFB_n, C=QN_m+QN_n) emits the exp2 argument directly.

#define OFF_SC  0
#define OFF_AF  16        // 16384 bf16 = 8192 f
#define OFF_QFB 8208      // 294912 f (589824 bf16)
#define OFF_QFA 303120    // 294912 f
#define OFF_QN  598032    // 36864 f
#define OFF_XF  634896    // 294912 f
#define OFF_F2  929808    // 1179648 f (2359296 bf16)
#define OFF_CAT 2109456   // 589824 f
// total 2699280 floats = 10.8 MB

#define LOG2E 1.44269504f

typedef __attribute__((ext_vector_type(8))) short bf16x8;
typedef __attribute__((ext_vector_type(16))) float f32x16;
union U4 { uint4 u; bf16x8 b; };

__device__ __forceinline__ unsigned short f2bf(float x) {
    unsigned int u = __float_as_uint(x);
    unsigned int r = u + 0x7fffu + ((u >> 16) & 1u);
    return (unsigned short)(r >> 16);
}

__global__ __launch_bounds__(256) void k_bound(
    const float* __restrict__ Wq, const float* __restrict__ Wv,
    const float* __restrict__ Wo, const float* __restrict__ gamma, float* ws)
{
    __shared__ double red[256];
    __shared__ double sums[9];
    int t = threadIdx.x;
    for (int ph = 0; ph < 9; ++ph) {
        double s = 0.0;
        if (ph < 4) {
            const float* W = Wq + ph * 1024;
            for (int i = t; i < 1024; i += 256) { double v = W[i]; s += v * v; }
        } else if (ph < 8) {
            const float* W = Wv + (ph - 4) * 1024;
            for (int i = t; i < 1024; i += 256) { double v = W[i]; s += v * v; }
        } else {
            for (int i = t; i < 4096; i += 256) { double v = Wo[i]; s += v * v; }
        }
        red[t] = s; __syncthreads();
        for (int off = 128; off; off >>= 1) {
            if (t < off) red[t] += red[t + off];
            __syncthreads();
        }
        if (t == 0) sums[ph] = red[0];
        __syncthreads();
    }
    if (t == 0) {
        // W0(N/e) Newton in f32 (HW transcendentals); rel err ~1e-7, ample
        float z = 2304.0f / 2.7182818284590452f;
        float w = logf(z) - logf(logf(z));
        #pragma unroll 1
        for (int it = 0; it < 30; ++it) {
            float ew = __expf(w);
            w = w - (w * ew - z) / (ew * (w + 1.0f));
        }
        double phi = (double)w;
        double term = sqrt(sums[0]*sums[4] + sums[1]*sums[5] +
                           sums[2]*sums[6] + sums[3]*sums[7]);
        double bound = 6.0 * (4.0 * phi + 1.0) * term * sqrt(sums[8]);
        ws[OFF_SC] = (float)((double)gamma[0] / bound);
    }
}

// A[h] = WqR @ WqR^T / 4 in bf16 frag layout. 64 blocks x 256 thr.
__global__ __launch_bounds__(256) void k_A(const float* __restrict__ Wq, float* ws)
{
    __shared__ float WlP[64 * 17];   // [d][k] pitch 17 (bank-spread for e-side reads)
    int bid = blockIdx.x, h = bid >> 4, dq = bid & 15, t = threadIdx.x;
    const float* W = Wq + h * 1024;
    for (int i = t; i < 1024; i += 256) WlP[(i >> 4) * 17 + (i & 15)] = W[i];
    __syncthreads();
    int dl = t >> 6, e = t & 63, d = dq * 4 + dl;
    float s = 0.f;
    #pragma unroll
    for (int k = 0; k < 16; ++k) s += WlP[d * 17 + k] * WlP[e * 17 + k];
    int tt = d >> 4, j = d & 7, l = ((d >> 3) & 1) * 32 + (e & 31), ec = e >> 5;
    unsigned short* af = (unsigned short*)(ws + OFF_AF);
    af[(((h * 4 + tt) * 2 + ec) * 64 + l) * 8 + j] = f2bf(0.25f * s);
}

// q = Wq*x_flat + bq. Writes QFA (scaled) + QFB frag layouts + QN. 288 x 128.
__global__ __launch_bounds__(128) void k_q(
    const float* __restrict__ x, const float* __restrict__ Wq,
    const float* __restrict__ bq, float* ws)
{
    __shared__ float WlT[1024];   // [d][k]
    __shared__ float bl[16];
    int bid = blockIdx.x, bh = bid / 18, nt = bid % 18;
    int h = bh & 3, b = bh >> 2, t = threadIdx.x;
    const float* W = Wq + h * 1024;
    for (int i = t; i < 1024; i += 128) WlT[(i & 63) * 16 + (i >> 6)] = W[i];
    if (t < 16) bl[t] = bq[h * 16 + t];
    __syncthreads();
    int n = nt * 128 + t;
    const float* xb = x + (size_t)b * 147456;
    float q[16];
    #pragma unroll
    for (int k = 0; k < 16; ++k) q[k] = bl[k];
    const float4* Wt4 = (const float4*)WlT;
    for (int d = 0; d < 64; ++d) {
        float xv = xb[d * 2304 + n];
        float4 wa = Wt4[d * 4 + 0], wb = Wt4[d * 4 + 1];
        float4 wc = Wt4[d * 4 + 2], wd = Wt4[d * 4 + 3];
        q[0]=fmaf(wa.x,xv,q[0]);  q[1]=fmaf(wa.y,xv,q[1]);
        q[2]=fmaf(wa.z,xv,q[2]);  q[3]=fmaf(wa.w,xv,q[3]);
        q[4]=fmaf(wb.x,xv,q[4]);  q[5]=fmaf(wb.y,xv,q[5]);
        q[6]=fmaf(wb.z,xv,q[6]);  q[7]=fmaf(wb.w,xv,q[7]);
        q[8]=fmaf(wc.x,xv,q[8]);  q[9]=fmaf(wc.y,xv,q[9]);
        q[10]=fmaf(wc.z,xv,q[10]); q[11]=fmaf(wc.w,xv,q[11]);
        q[12]=fmaf(wd.x,xv,q[12]); q[13]=fmaf(wd.y,xv,q[13]);
        q[14]=fmaf(wd.z,xv,q[14]); q[15]=fmaf(wd.w,xv,q[15]);
    }
    float qn = 0.f;
    #pragma unroll
    for (int k = 0; k < 16; ++k) qn = fmaf(q[k], q[k], qn);
    ws[OFF_QN + bh * 2304 + n] = -0.25f * LOG2E * qn;
    unsigned int pkB[8], pkA[8];
    const float sA = 0.5f * LOG2E;
    #pragma unroll
    for (int i = 0; i < 8; ++i) {
        pkB[i] = (unsigned int)f2bf(q[2*i]) | ((unsigned int)f2bf(q[2*i+1]) << 16);
        pkA[i] = (unsigned int)f2bf(sA*q[2*i]) | ((unsigned int)f2bf(sA*q[2*i+1]) << 16);
    }
    size_t cbase = (size_t)(bh * 72 + (n >> 5)) * 64;
    uint4* qb4 = (uint4*)((unsigned short*)(ws + OFF_QFB)) + cbase;
    uint4* qa4 = (uint4*)((unsigned short*)(ws + OFF_QFA)) + cbase;
    qb4[n & 31]        = make_uint4(pkB[0], pkB[1], pkB[2], pkB[3]);
    qb4[32 + (n & 31)] = make_uint4(pkB[4], pkB[5], pkB[6], pkB[7]);
    qa4[n & 31]        = make_uint4(pkA[0], pkA[1], pkA[2], pkA[3]);
    qa4[32 + (n & 31)] = make_uint4(pkA[4], pkA[5], pkA[6], pkA[7]);
}

// XF[b][T][dc][lane][j] = bf16( x_r[b][16T + (lane>>5)*8 + j][dc*32 + (lane&31)] )
__global__ __launch_bounds__(256) void k_xf(const float* __restrict__ x, float* ws)
{
    int i = blockIdx.x * 256 + threadIdx.x;
    int l = i & 63, c1 = i >> 6;
    int dc = c1 & 1, c2 = c1 >> 1;
    int T = c2 % 144, b = c2 / 144;
    const float* xb = x + (size_t)b * 147456;
    int col = dc * 32 + (l & 31), mbase = 16 * T + (l >> 5) * 8;
    unsigned int pk[4];
    #pragma unroll
    for (int jj = 0; jj < 4; ++jj) {
        float f0 = xb[(mbase + 2*jj) * 64 + col];
        float f1 = xb[(mbase + 2*jj + 1) * 64 + col];
        pk[jj] = (unsigned int)f2bf(f0) | ((unsigned int)f2bf(f1) << 16);
    }
    ((uint4*)((unsigned short*)(ws + OFF_XF)))[i] = make_uint4(pk[0], pk[1], pk[2], pk[3]);
}

// Streaming (max-free) attention. Block = 2 waves = 32 q-rows; waves split m.
__global__ __launch_bounds__(128, 3) void k_attn(float* __restrict__ ws)
{
    __shared__ __align__(16) float Ols[2][32][68];
    __shared__ float Lls[2][32];
    __shared__ __align__(16) unsigned short fls[32][80];

    const int t = threadIdx.x, w = t >> 6, lane = t & 63;
    const int bid = blockIdx.x, bh = bid / 72, rc = bid % 72;
    const int h = bh & 3;
    const int b = bh >> 2;
    const int hi = lane >> 5, nl = lane & 31, s4 = hi * 4;

    const uint4* QB = (const uint4*)((const unsigned short*)(ws + OFF_QFB)) + (size_t)bh * 4608;
    const uint4* QA = (const uint4*)((const unsigned short*)(ws + OFF_QFA)) + (size_t)bh * 4608;
    const uint4* XF = (const uint4*)((const unsigned short*)(ws + OFF_XF)) + (size_t)b * 18432;
    const float* qn = ws + OFF_QN + bh * 2304;

    U4 qb; qb.u = QB[rc * 64 + lane];     // B-frag: own 32 q-rows (col n = lane&31)
    const float qoffl = qn[rc * 32 + nl]; // -0.25*log2e*|q_n|^2 for this lane's n

    f32x16 O0, O1;
    #pragma unroll
    for (int i = 0; i < 16; ++i) { O0[i] = 0.f; O1[i] = 0.f; }
    float lrun = 0.f;

    for (int mt = w; mt < 36; mt += 2) {
        const int m0 = mt * 64;
        U4 xv[8];
        #pragma unroll
        for (int q = 0; q < 8; ++q) xv[q].u = XF[(size_t)(mt * 8 + q) * 64 + lane];
        U4 a0, a1;
        a0.u = QA[(mt * 2) * 64 + lane];
        a1.u = QA[(mt * 2 + 1) * 64 + lane];
        f32x16 c0, c1;
        #pragma unroll
        for (int g = 0; g < 4; ++g) {
            float4 t4 = *(const float4*)(qn + m0 + 8 * g + s4);
            c0[4*g+0] = t4.x + qoffl; c0[4*g+1] = t4.y + qoffl;
            c0[4*g+2] = t4.z + qoffl; c0[4*g+3] = t4.w + qoffl;
            float4 u4 = *(const float4*)(qn + m0 + 32 + 8 * g + s4);
            c1[4*g+0] = u4.x + qoffl; c1[4*g+1] = u4.y + qoffl;
            c1[4*g+2] = u4.z + qoffl; c1[4*g+3] = u4.w + qoffl;
        }
        // w_log2 = log2e*(0.5 q_m.q_n - 0.25 qn_m - 0.25 qn_n)  (<= ~0)
        f32x16 s0 = __builtin_amdgcn_mfma_f32_32x32x16_bf16(a0.b, qb.b, c0, 0, 0, 0);
        f32x16 s1 = __builtin_amdgcn_mfma_f32_32x32x16_bf16(a1.b, qb.b, c1, 0, 0, 0);
        float p[32];
        #pragma unroll
        for (int r = 0; r < 16; ++r)
            asm("v_exp_f32 %0, %1" : "=v"(p[r]) : "v"(s0[r]));
        #pragma unroll
        for (int r = 0; r < 16; ++r)
            asm("v_exp_f32 %0, %1" : "=v"(p[16 + r]) : "v"(s1[r]));
        float la = 0.f, lb = 0.f, lc = 0.f, ld = 0.f;
        #pragma unroll
        for (int r = 0; r < 32; r += 4) {
            la += p[r]; lb += p[r+1]; lc += p[r+2]; ld += p[r+3];
        }
        lrun += (la + lb) + (lc + ld);
        // P -> bf16 A-frags (validated exchange), PV MFMAs
        #pragma unroll
        for (int c = 0; c < 2; ++c) {
            unsigned int wd[8], xd[8];
            #pragma unroll
            for (int i = 0; i < 8; ++i)
                asm("v_cvt_pk_bf16_f32 %0, %1, %2"
                    : "=v"(wd[i]) : "v"(p[c*16 + 2*i]), "v"(p[c*16 + 2*i + 1]));
            #pragma unroll
            for (int i = 0; i < 8; ++i) xd[i] = (unsigned int)__shfl_xor((int)wd[i], 32);
            U4 af0, af1;
            af0.u.x = hi ? xd[2] : wd[0];  af0.u.y = hi ? xd[3] : wd[1];
            af0.u.z = hi ? wd[2] : xd[0];  af0.u.w = hi ? wd[3] : xd[1];
            af1.u.x = hi ? xd[6] : wd[4];  af1.u.y = hi ? xd[7] : wd[5];
            af1.u.z = hi ? wd[6] : xd[4];  af1.u.w = hi ? wd[7] : xd[5];
            O0 = __builtin_amdgcn_mfma_f32_32x32x16_bf16(af0.b, xv[4*c+0].b, O0, 0, 0, 0);
            O1 = __builtin_amdgcn_mfma_f32_32x32x16_bf16(af0.b, xv[4*c+1].b, O1, 0, 0, 0);
            O0 = __builtin_amdgcn_mfma_f32_32x32x16_bf16(af1.b, xv[4*c+2].b, O0, 0, 0, 0);
            O1 = __builtin_amdgcn_mfma_f32_32x32x16_bf16(af1.b, xv[4*c+3].b, O1, 0, 0, 0);
        }
    }

    // partial state -> LDS
    lrun += __shfl_xor(lrun, 32);
    #pragma unroll
    for (int r = 0; r < 16; ++r) {
        int n = (r & 3) + 8 * (r >> 2) + s4;
        Ols[w][n][nl]      = O0[r];
        Ols[w][n][nl + 32] = O1[r];
    }
    if (!hi) Lls[w][nl] = lrun;
    __syncthreads();

    // combine 2 partials, normalize, write f as bf16 tile
    {
        int n = t >> 2, ds = (t & 3) * 16;
        float invL = 1.f / (Lls[0][n] + Lls[1][n]);
        float f[16];
        #pragma unroll
        for (int j = 0; j < 16; ++j)
            f[j] = (Ols[0][n][ds + j] + Ols[1][n][ds + j]) * invL;
        unsigned int pk[8];
        #pragma unroll
        for (int i = 0; i < 8; ++i)
            asm("v_cvt_pk_bf16_f32 %0, %1, %2" : "=v"(pk[i]) : "v"(f[2*i]), "v"(f[2*i+1]));
        char* dst = (char*)&fls[0][0] + n * 160 + ds * 2;
        *(uint4*)(dst)      = make_uint4(pk[0], pk[1], pk[2], pk[3]);
        *(uint4*)(dst + 16) = make_uint4(pk[4], pk[5], pk[6], pk[7]);
    }
    __syncthreads();

    // f2 = f @ A : wave w handles e-columns w*32..+31; store bf16
    {
        const int ec = w;
        const uint4* AFp = (const uint4*)((const unsigned short*)(ws + OFF_AF)) + h * 512;
        f32x16 acc;
        #pragma unroll
        for (int i = 0; i < 16; ++i) acc[i] = 0.f;
        #pragma unroll
        for (int tt = 0; tt < 4; ++tt) {
            U4 a, bb;
            a.u  = *(const uint4*)((const char*)&fls[0][0] + nl * 160 + tt * 32 + hi * 16);
            bb.u = AFp[(tt * 2 + ec) * 64 + lane];
            acc = __builtin_amdgcn_mfma_f32_32x32x16_bf16(a.b, bb.b, acc, 0, 0, 0);
        }
        unsigned short* f2g = (unsigned short*)(ws + OFF_F2) +
                              (size_t)bh * 147456 + (size_t)rc * 32 * 64;
        #pragma unroll
        for (int r = 0; r < 16; ++r)
            f2g[((r & 3) + 8 * (r >> 2) + s4) * 64 + ec * 32 + nl] = f2bf(acc[r]);
    }
}

// v = Wv*f_img + bv scattered into cat (f_img read through flat reinterpret)
__global__ __launch_bounds__(128) void k_v(
    const float* __restrict__ Wv, const float* __restrict__ bv, float* ws)
{
    __shared__ float WlT[1024];
    __shared__ float bl[16];
    int bid = blockIdx.x, bh = bid / 18, nt = bid % 18;
    int h = bh & 3, b = bh >> 2, t = threadIdx.x;
    const float* W = Wv + h * 1024;
    for (int i = t; i < 1024; i += 128) WlT[(i & 63) * 16 + (i >> 6)] = W[i];
    if (t < 16) bl[t] = bv[h * 16 + t];
    __syncthreads();
    int n = nt * 128 + t;
    const unsigned short* f2g = (const unsigned short*)(ws + OFF_F2) + (size_t)bh * 147456;
    float v[16];
    #pragma unroll
    for (int k = 0; k < 16; ++k) v[k] = bl[k];
    const float4* Wt4 = (const float4*)WlT;
    for (int d = 0; d < 64; ++d) {
        float fv = __uint_as_float((unsigned int)f2g[d * 2304 + n] << 16);
        float4 wa = Wt4[d * 4 + 0], wb = Wt4[d * 4 + 1];
        float4 wc = Wt4[d * 4 + 2], wd = Wt4[d * 4 + 3];
        v[0]=fmaf(wa.x,fv,v[0]);  v[1]=fmaf(wa.y,fv,v[1]);
        v[2]=fmaf(wa.z,fv,v[2]);  v[3]=fmaf(wa.w,fv,v[3]);
        v[4]=fmaf(wb.x,fv,v[4]);  v[5]=fmaf(wb.y,fv,v[5]);
        v[6]=fmaf(wb.z,fv,v[6]);  v[7]=fmaf(wb.w,fv,v[7]);
        v[8]=fmaf(wc.x,fv,v[8]);  v[9]=fmaf(wc.y,fv,v[9]);
        v[10]=fmaf(wc.z,fv,v[10]); v[11]=fmaf(wc.w,fv,v[11]);
        v[12]=fmaf(wd.x,fv,v[12]); v[13]=fmaf(wd.y,fv,v[13]);
        v[14]=fmaf(wd.z,fv,v[14]); v[15]=fmaf(wd.w,fv,v[15]);
    }
    float* cat = ws + OFF_CAT + (size_t)b * 147456;
    #pragma unroll
    for (int k = 0; k < 16; ++k) {
        int j = k * 2304 + n;
        cat[(j >> 4) * 64 + h * 16 + (j & 15)] = v[k];
    }
}

// out = sc*(Wo@cat_img + bo) + x
__global__ __launch_bounds__(128) void k_out(
    const float* __restrict__ x, const float* __restrict__ Wo,
    const float* __restrict__ bo, const float* ws, float* __restrict__ out)
{
    __shared__ float Wl[1024];   // [d][oo] (contiguous oo -> b128 reads)
    __shared__ float bl[16];
    int bid = blockIdx.x;
    int b = bid / 72, rem = bid % 72, nt = rem >> 2, og = rem & 3;
    int t = threadIdx.x;
    for (int idx = t; idx < 1024; idx += 128) {
        int d = idx >> 4, oo = idx & 15;
        Wl[idx] = Wo[(og * 16 + oo) * 64 + d];
    }
    if (t < 16) bl[t] = bo[og * 16 + t];
    __syncthreads();
    int n = nt * 128 + t;
    const float* cat = ws + OFF_CAT + (size_t)b * 147456;
    float acc[16];
    #pragma unroll
    for (int oo = 0; oo < 16; ++oo) acc[oo] = bl[oo];
    const float4* Wt4 = (const float4*)Wl;
    for (int d = 0; d < 64; ++d) {
        float cv = cat[d * 2304 + n];
        float4 wa = Wt4[d * 4 + 0], wb = Wt4[d * 4 + 1];
        float4 wc = Wt4[d * 4 + 2], wd = Wt4[d * 4 + 3];
        acc[0]=fmaf(wa.x,cv,acc[0]);  acc[1]=fmaf(wa.y,cv,acc[1]);
        acc[2]=fmaf(wa.z,cv,acc[2]);  acc[3]=fmaf(wa.w,cv,acc[3]);
        acc[4]=fmaf(wb.x,cv,acc[4]);  acc[5]=fmaf(wb.y,cv,acc[5]);
        acc[6]=fmaf(wb.z,cv,acc[6]);  acc[7]=fmaf(wb.w,cv,acc[7]);
        acc[8]=fmaf(wc.x,cv,acc[8]);  acc[9]=fmaf(wc.y,cv,acc[9]);
        acc[10]=fmaf(wc.z,cv,acc[10]); acc[11]=fmaf(wc.w,cv,acc[11]);
        acc[12]=fmaf(wd.x,cv,acc[12]); acc[13]=fmaf(wd.y,cv,acc[13]);
        acc[14]=fmaf(wd.z,cv,acc[14]); acc[15]=fmaf(wd.w,cv,acc[15]);
    }
    float sc = ws[OFF_SC];
    const float* xb = x + (size_t)b * 147456;
    float* ob = out + (size_t)b * 147456;
    #pragma unroll
    for (int oo = 0; oo < 16; ++oo) {
        int o = og * 16 + oo;
        ob[o * 2304 + n] = fmaf(sc, acc[oo], xb[o * 2304 + n]);
    }
}

extern "C" void kernel_launch(void* const* d_in, const int* in_sizes, int n_in,
                              void* d_out, int out_size, void* d_ws, size_t ws_size,
                              hipStream_t stream) {
    const float* x     = (const float*)d_in[0];
    const float* Wq    = (const float*)d_in[1];
    const float* bq    = (const float*)d_in[2];
    const float* Wv    = (const float*)d_in[3];
    const float* bv    = (const float*)d_in[4];
    const float* Wo    = (const float*)d_in[5];
    const float* bo    = (const float*)d_in[6];
    const float* gamma = (const float*)d_in[7];
    float* out = (float*)d_out;
    float* ws  = (float*)d_ws;
    k_bound<<<1,    256, 0, stream>>>(Wq, Wv, Wo, gamma, ws);
    k_A    <<<64,   256, 0, stream>>>(Wq, ws);
    k_q    <<<288,  128, 0, stream>>>(x, Wq, bq, ws);
    k_xf   <<<288,  256, 0, stream>>>(x, ws);
    k_attn <<<1152, 128, 0, stream>>>(ws);
    k_v    <<<288,  128, 0, stream>>>(Wv, bv, ws);
    k_out  <<<288,  128, 0, stream>>>(x, Wo, bo, ws, out);
}

// Round 7
// 133.417 us; speedup vs baseline: 4.3302x; 1.2245x over previous
//
#include <hip/hip_runtime.h>
#include <math.h>

// B=4, D=64, N=2304, heads=4, dh=16, scalar=4. Attention output divided by
// bound~2100 => bf16 in the attention branch is ample precision.
// Max-free softmax: logits = -dist/4 with full -0.25*qn_n shift => row max = 0.
// exp2-folding: QFA = bf16(0.5*log2e*q), QFB = bf16(q), QN = -0.25*log2e*|q|^2.

#define OFF_SC  0
#define OFF_AF  16        // 16384 bf16
#define OFF_QFB 8208      // 589824 bf16
#define OFF_QFA 303120    // 589824 bf16
#define OFF_QN  598032    // 36864 f32
#define OFF_XF  634896    // 589824 bf16
#define OFF_F2  929808    // 2359296 bf16
// total ~8.4 MB of d_ws

#define LOG2E 1.44269504f

typedef __attribute__((ext_vector_type(8))) short bf16x8;
typedef __attribute__((ext_vector_type(16))) float f32x16;
union U4 { uint4 u; bf16x8 b; };

__device__ __forceinline__ unsigned short f2bf(float x) {
    unsigned int u = __float_as_uint(x);
    unsigned int r = u + 0x7fffu + ((u >> 16) & 1u);
    return (unsigned short)(r >> 16);
}
__device__ __forceinline__ float bf2f(unsigned short v) {
    return __uint_as_float((unsigned int)v << 16);
}

// Fused prep: role by blockIdx. 0: bound; 1..64: A; 65..640: q; 641..928: xf.
__global__ __launch_bounds__(256) void k_prep(
    const float* __restrict__ x, const float* __restrict__ Wq,
    const float* __restrict__ bq, const float* __restrict__ Wv,
    const float* __restrict__ Wo, const float* __restrict__ gamma, float* ws)
{
    __shared__ __align__(16) char smem[8192];
    const int bid = blockIdx.x, t = threadIdx.x;

    if (bid == 0) {
        // ---- bound role ----
        double* red  = (double*)smem;          // 256 doubles
        double* sums = (double*)(smem + 2048); // 9 doubles
        for (int ph = 0; ph < 9; ++ph) {
            double s = 0.0;
            if (ph < 4) {
                const float* W = Wq + ph * 1024;
                for (int i = t; i < 1024; i += 256) { double v = W[i]; s += v * v; }
            } else if (ph < 8) {
                const float* W = Wv + (ph - 4) * 1024;
                for (int i = t; i < 1024; i += 256) { double v = W[i]; s += v * v; }
            } else {
                for (int i = t; i < 4096; i += 256) { double v = Wo[i]; s += v * v; }
            }
            red[t] = s; __syncthreads();
            for (int off = 128; off; off >>= 1) {
                if (t < off) red[t] += red[t + off];
                __syncthreads();
            }
            if (t == 0) sums[ph] = red[0];
            __syncthreads();
        }
        if (t == 0) {
            float z = 2304.0f / 2.7182818284590452f;
            float w = logf(z) - logf(logf(z));
            #pragma unroll 1
            for (int it = 0; it < 30; ++it) {
                float ew = __expf(w);
                w = w - (w * ew - z) / (ew * (w + 1.0f));
            }
            double phi = (double)w;
            double term = sqrt(sums[0]*sums[4] + sums[1]*sums[5] +
                               sums[2]*sums[6] + sums[3]*sums[7]);
            double bound = 6.0 * (4.0 * phi + 1.0) * term * sqrt(sums[8]);
            ws[OFF_SC] = (float)((double)gamma[0] / bound);
        }
    } else if (bid <= 64) {
        // ---- A role: A[h] = WqR@WqR^T/4 in bf16 frag layout ----
        float* WlP = (float*)smem;   // [64][17]
        int id = bid - 1, h = id >> 4, dq = id & 15;
        const float* W = Wq + h * 1024;
        for (int i = t; i < 1024; i += 256) WlP[(i >> 4) * 17 + (i & 15)] = W[i];
        __syncthreads();
        int dl = t >> 6, e = t & 63, d = dq * 4 + dl;
        float s = 0.f;
        #pragma unroll
        for (int k = 0; k < 16; ++k) s += WlP[d * 17 + k] * WlP[e * 17 + k];
        int tt = d >> 4, j = d & 7, l = ((d >> 3) & 1) * 32 + (e & 31), ec = e >> 5;
        unsigned short* af = (unsigned short*)(ws + OFF_AF);
        af[(((h * 4 + tt) * 2 + ec) * 64 + l) * 8 + j] = f2bf(0.25f * s);
    } else if (bid <= 640) {
        // ---- q role: thread = (n, k-quad). 576 blocks = 16 bh x 36 n-tiles ----
        float* WlT = (float*)smem;           // [64][16]
        float* bl  = (float*)(smem + 4096);  // 16
        float* qnp = (float*)(smem + 4160);  // [4][64]
        int rb = bid - 65, bh = rb / 36, nb = rb % 36;
        int h = bh & 3, b = bh >> 2;
        const float* W = Wq + h * 1024;
        for (int i = t; i < 1024; i += 256) WlT[(i & 63) * 16 + (i >> 6)] = W[i];
        if (t < 16) bl[t] = bq[h * 16 + t];
        __syncthreads();
        int nl = t & 63, kg = t >> 6, n = nb * 64 + nl;
        const float* xb = x + (size_t)b * 147456;
        const float4* wrow = (const float4*)WlT;   // [d][4 quads]
        float q0 = bl[kg*4], q1 = bl[kg*4+1], q2 = bl[kg*4+2], q3 = bl[kg*4+3];
        for (int d = 0; d < 64; ++d) {
            float xv = xb[d * 2304 + n];
            float4 wv = wrow[d * 4 + kg];
            q0 = fmaf(wv.x, xv, q0); q1 = fmaf(wv.y, xv, q1);
            q2 = fmaf(wv.z, xv, q2); q3 = fmaf(wv.w, xv, q3);
        }
        qnp[kg * 64 + nl] = q0*q0 + q1*q1 + q2*q2 + q3*q3;
        unsigned pB0 = (unsigned)f2bf(q0) | ((unsigned)f2bf(q1) << 16);
        unsigned pB1 = (unsigned)f2bf(q2) | ((unsigned)f2bf(q3) << 16);
        const float sA = 0.5f * LOG2E;
        unsigned pA0 = (unsigned)f2bf(sA*q0) | ((unsigned)f2bf(sA*q1) << 16);
        unsigned pA1 = (unsigned)f2bf(sA*q2) | ((unsigned)f2bf(sA*q3) << 16);
        // pair p = k/2: chunk = p>>2 = kg>>1, uint offset within chunk = (kg&1)*2
        size_t base = (size_t)(bh * 72 + (n >> 5)) * 256
                    + (size_t)(((kg >> 1) * 32 + (n & 31)) * 4 + (kg & 1) * 2);
        *(uint2*)((unsigned*)((unsigned short*)(ws + OFF_QFB)) + base) = make_uint2(pB0, pB1);
        *(uint2*)((unsigned*)((unsigned short*)(ws + OFF_QFA)) + base) = make_uint2(pA0, pA1);
        __syncthreads();
        if (t < 64) {
            float qn = qnp[t] + qnp[64 + t] + qnp[128 + t] + qnp[192 + t];
            ws[OFF_QN + bh * 2304 + nb * 64 + t] = -0.25f * LOG2E * qn;
        }
    } else {
        // ---- xf role: XF[b][T][dc][lane][j] frag transpose of x_r ----
        int i = (bid - 641) * 256 + t;
        int l = i & 63, c1 = i >> 6;
        int dc = c1 & 1, c2 = c1 >> 1;
        int T = c2 % 144, b = c2 / 144;
        const float* xb = x + (size_t)b * 147456;
        int col = dc * 32 + (l & 31), mbase = 16 * T + (l >> 5) * 8;
        unsigned int pk[4];
        #pragma unroll
        for (int jj = 0; jj < 4; ++jj) {
            float f0 = xb[(mbase + 2*jj) * 64 + col];
            float f1 = xb[(mbase + 2*jj + 1) * 64 + col];
            pk[jj] = (unsigned int)f2bf(f0) | ((unsigned int)f2bf(f1) << 16);
        }
        ((uint4*)((unsigned short*)(ws + OFF_XF)))[i] = make_uint4(pk[0], pk[1], pk[2], pk[3]);
    }
}

// Streaming (max-free) attention. Block = 2 waves = 32 q-rows; waves split m.
// UNCHANGED from validated R6 kernel.
__global__ __launch_bounds__(128, 3) void k_attn(float* __restrict__ ws)
{
    __shared__ __align__(16) float Ols[2][32][68];
    __shared__ float Lls[2][32];
    __shared__ __align__(16) unsigned short fls[32][80];

    const int t = threadIdx.x, w = t >> 6, lane = t & 63;
    const int bid = blockIdx.x, bh = bid / 72, rc = bid % 72;
    const int h = bh & 3;
    const int b = bh >> 2;
    const int hi = lane >> 5, nl = lane & 31, s4 = hi * 4;

    const uint4* QB = (const uint4*)((const unsigned short*)(ws + OFF_QFB)) + (size_t)bh * 4608;
    const uint4* QA = (const uint4*)((const unsigned short*)(ws + OFF_QFA)) + (size_t)bh * 4608;
    const uint4* XF = (const uint4*)((const unsigned short*)(ws + OFF_XF)) + (size_t)b * 18432;
    const float* qn = ws + OFF_QN + bh * 2304;

    U4 qb; qb.u = QB[rc * 64 + lane];
    const float qoffl = qn[rc * 32 + nl];

    f32x16 O0, O1;
    #pragma unroll
    for (int i = 0; i < 16; ++i) { O0[i] = 0.f; O1[i] = 0.f; }
    float lrun = 0.f;

    for (int mt = w; mt < 36; mt += 2) {
        const int m0 = mt * 64;
        U4 xv[8];
        #pragma unroll
        for (int q = 0; q < 8; ++q) xv[q].u = XF[(size_t)(mt * 8 + q) * 64 + lane];
        U4 a0, a1;
        a0.u = QA[(mt * 2) * 64 + lane];
        a1.u = QA[(mt * 2 + 1) * 64 + lane];
        f32x16 c0, c1;
        #pragma unroll
        for (int g = 0; g < 4; ++g) {
            float4 t4 = *(const float4*)(qn + m0 + 8 * g + s4);
            c0[4*g+0] = t4.x + qoffl; c0[4*g+1] = t4.y + qoffl;
            c0[4*g+2] = t4.z + qoffl; c0[4*g+3] = t4.w + qoffl;
            float4 u4 = *(const float4*)(qn + m0 + 32 + 8 * g + s4);
            c1[4*g+0] = u4.x + qoffl; c1[4*g+1] = u4.y + qoffl;
            c1[4*g+2] = u4.z + qoffl; c1[4*g+3] = u4.w + qoffl;
        }
        f32x16 s0 = __builtin_amdgcn_mfma_f32_32x32x16_bf16(a0.b, qb.b, c0, 0, 0, 0);
        f32x16 s1 = __builtin_amdgcn_mfma_f32_32x32x16_bf16(a1.b, qb.b, c1, 0, 0, 0);
        float p[32];
        #pragma unroll
        for (int r = 0; r < 16; ++r)
            asm("v_exp_f32 %0, %1" : "=v"(p[r]) : "v"(s0[r]));
        #pragma unroll
        for (int r = 0; r < 16; ++r)
            asm("v_exp_f32 %0, %1" : "=v"(p[16 + r]) : "v"(s1[r]));
        float la = 0.f, lb = 0.f, lc = 0.f, ld = 0.f;
        #pragma unroll
        for (int r = 0; r < 32; r += 4) {
            la += p[r]; lb += p[r+1]; lc += p[r+2]; ld += p[r+3];
        }
        lrun += (la + lb) + (lc + ld);
        #pragma unroll
        for (int c = 0; c < 2; ++c) {
            unsigned int wd[8], xd[8];
            #pragma unroll
            for (int i = 0; i < 8; ++i)
                asm("v_cvt_pk_bf16_f32 %0, %1, %2"
                    : "=v"(wd[i]) : "v"(p[c*16 + 2*i]), "v"(p[c*16 + 2*i + 1]));
            #pragma unroll
            for (int i = 0; i < 8; ++i) xd[i] = (unsigned int)__shfl_xor((int)wd[i], 32);
            U4 af0, af1;
            af0.u.x = hi ? xd[2] : wd[0];  af0.u.y = hi ? xd[3] : wd[1];
            af0.u.z = hi ? wd[2] : xd[0];  af0.u.w = hi ? wd[3] : xd[1];
            af1.u.x = hi ? xd[6] : wd[4];  af1.u.y = hi ? xd[7] : wd[5];
            af1.u.z = hi ? wd[6] : xd[4];  af1.u.w = hi ? wd[7] : xd[5];
            O0 = __builtin_amdgcn_mfma_f32_32x32x16_bf16(af0.b, xv[4*c+0].b, O0, 0, 0, 0);
            O1 = __builtin_amdgcn_mfma_f32_32x32x16_bf16(af0.b, xv[4*c+1].b, O1, 0, 0, 0);
            O0 = __builtin_amdgcn_mfma_f32_32x32x16_bf16(af1.b, xv[4*c+2].b, O0, 0, 0, 0);
            O1 = __builtin_amdgcn_mfma_f32_32x32x16_bf16(af1.b, xv[4*c+3].b, O1, 0, 0, 0);
        }
    }

    lrun += __shfl_xor(lrun, 32);
    #pragma unroll
    for (int r = 0; r < 16; ++r) {
        int n = (r & 3) + 8 * (r >> 2) + s4;
        Ols[w][n][nl]      = O0[r];
        Ols[w][n][nl + 32] = O1[r];
    }
    if (!hi) Lls[w][nl] = lrun;
    __syncthreads();

    {
        int n = t >> 2, ds = (t & 3) * 16;
        float invL = 1.f / (Lls[0][n] + Lls[1][n]);
        float f[16];
        #pragma unroll
        for (int j = 0; j < 16; ++j)
            f[j] = (Ols[0][n][ds + j] + Ols[1][n][ds + j]) * invL;
        unsigned int pk[8];
        #pragma unroll
        for (int i = 0; i < 8; ++i)
            asm("v_cvt_pk_bf16_f32 %0, %1, %2" : "=v"(pk[i]) : "v"(f[2*i]), "v"(f[2*i+1]));
        char* dst = (char*)&fls[0][0] + n * 160 + ds * 2;
        *(uint4*)(dst)      = make_uint4(pk[0], pk[1], pk[2], pk[3]);
        *(uint4*)(dst + 16) = make_uint4(pk[4], pk[5], pk[6], pk[7]);
    }
    __syncthreads();

    {
        const int ec = w;
        const uint4* AFp = (const uint4*)((const unsigned short*)(ws + OFF_AF)) + h * 512;
        f32x16 acc;
        #pragma unroll
        for (int i = 0; i < 16; ++i) acc[i] = 0.f;
        #pragma unroll
        for (int tt = 0; tt < 4; ++tt) {
            U4 a, bb;
            a.u  = *(const uint4*)((const char*)&fls[0][0] + nl * 160 + tt * 32 + hi * 16);
            bb.u = AFp[(tt * 2 + ec) * 64 + lane];
            acc = __builtin_amdgcn_mfma_f32_32x32x16_bf16(a.b, bb.b, acc, 0, 0, 0);
        }
        unsigned short* f2g = (unsigned short*)(ws + OFF_F2) +
                              (size_t)bh * 147456 + (size_t)rc * 32 * 64;
        #pragma unroll
        for (int r = 0; r < 16; ++r)
            f2g[((r & 3) + 8 * (r >> 2) + s4) * 64 + ec * 32 + nl] = f2bf(acc[r]);
    }
}

// Fused v+out: per target row n, the .view scatter collapses to
// k = n/144, np(c) = (n%144)*16 + c, col = h*16+c of the SAME row n.
// Block = 16 rows x (4h x 4cq | 16 o-quads). 576 blocks x 256.
__global__ __launch_bounds__(256) void k_post(
    const float* __restrict__ x, const float* __restrict__ Wv,
    const float* __restrict__ bv, const float* __restrict__ Wo,
    const float* __restrict__ bo, const float* __restrict__ ws,
    float* __restrict__ out)
{
    __shared__ float WvL[4096];      // [h][k][d]
    __shared__ float WoT[64 * 68];   // [d][o] pitch 68
    __shared__ float catL[16][68];
    __shared__ float bvL[64], boL[64];
    __shared__ float scs;
    const int bid = blockIdx.x, t = threadIdx.x;
    const int b = bid / 144, n0 = (bid % 144) * 16;
    for (int i = t; i < 4096; i += 256) WvL[i] = Wv[i];
    for (int i = t; i < 4096; i += 256) WoT[(i & 63) * 68 + (i >> 6)] = Wo[i];
    if (t < 64) { bvL[t] = bv[t]; boL[t] = bo[t]; }
    if (t == 0) scs = ws[OFF_SC];
    __syncthreads();

    const int nl = t & 15, q = t >> 4;
    const int n = n0 + nl;
    // ---- v phase: thread = (n, h, cq) ----
    {
        const int h = q >> 2, cq = q & 3;
        const int k = n / 144;
        const int np = (n % 144) * 16 + cq * 4;
        const unsigned short* f2p = (const unsigned short*)(ws + OFF_F2)
                                  + (size_t)(b * 4 + h) * 147456;
        const float* wv = WvL + h * 1024 + k * 64;
        float bvv = bvL[h * 16 + k];
        float v0 = bvv, v1 = bvv, v2 = bvv, v3 = bvv;
        for (int d = 0; d < 64; ++d) {
            ushort4 f4 = *(const ushort4*)(f2p + d * 2304 + np);
            float wd = wv[d];
            v0 = fmaf(wd, bf2f(f4.x), v0);
            v1 = fmaf(wd, bf2f(f4.y), v1);
            v2 = fmaf(wd, bf2f(f4.z), v2);
            v3 = fmaf(wd, bf2f(f4.w), v3);
        }
        int col = h * 16 + cq * 4;
        catL[nl][col + 0] = v0; catL[nl][col + 1] = v1;
        catL[nl][col + 2] = v2; catL[nl][col + 3] = v3;
    }
    __syncthreads();
    // ---- o phase: thread = (n, o-quad) ----
    {
        const int oq = q;
        const float4* wo4 = (const float4*)WoT;   // [d][17 float4], use index d*17+oq
        float a0 = boL[oq*4], a1 = boL[oq*4+1], a2 = boL[oq*4+2], a3 = boL[oq*4+3];
        for (int d = 0; d < 64; ++d) {
            float cv = catL[nl][d];
            float4 w4 = wo4[d * 17 + oq];
            a0 = fmaf(w4.x, cv, a0); a1 = fmaf(w4.y, cv, a1);
            a2 = fmaf(w4.z, cv, a2); a3 = fmaf(w4.w, cv, a3);
        }
        float sc = scs;
        const float* xb = x + (size_t)b * 147456;
        float* ob = out + (size_t)b * 147456;
        int o = oq * 4;
        ob[(o+0) * 2304 + n] = fmaf(sc, a0, xb[(o+0) * 2304 + n]);
        ob[(o+1) * 2304 + n] = fmaf(sc, a1, xb[(o+1) * 2304 + n]);
        ob[(o+2) * 2304 + n] = fmaf(sc, a2, xb[(o+2) * 2304 + n]);
        ob[(o+3) * 2304 + n] = fmaf(sc, a3, xb[(o+3) * 2304 + n]);
    }
}

extern "C" void kernel_launch(void* const* d_in, const int* in_sizes, int n_in,
                              void* d_out, int out_size, void* d_ws, size_t ws_size,
                              hipStream_t stream) {
    const float* x     = (const float*)d_in[0];
    const float* Wq    = (const float*)d_in[1];
    const float* bq    = (const float*)d_in[2];
    const float* Wv    = (const float*)d_in[3];
    const float* bv    = (const float*)d_in[4];
    const float* Wo    = (const float*)d_in[5];
    const float* bo    = (const float*)d_in[6];
    const float* gamma = (const float*)d_in[7];
    float* out = (float*)d_out;
    float* ws  = (float*)d_ws;
    k_prep<<<929,  256, 0, stream>>>(x, Wq, bq, Wv, Wo, gamma, ws);
    k_attn<<<1152, 128, 0, stream>>>(ws);
    k_post<<<576,  256, 0, stream>>>(x, Wv, bv, Wo, bo, ws, out);
}

// Round 8
// 129.687 us; speedup vs baseline: 4.4547x; 1.0288x over previous
//
#include <hip/hip_runtime.h>
#include <math.h>

// B=4, D=64, N=2304, heads=4, dh=16, scalar=4. Attention output divided by
// bound~2100 => bf16 in the attention branch is ample precision.
// Max-free softmax: logits = -dist/4 with full -0.25*qn_n shift => row max = 0.
// exp2-folding: QFA = bf16(0.5*log2e*q), QFB = bf16(q), QN = -0.25*log2e*|q|^2.

#define OFF_SC  0
#define OFF_AF  16        // 16384 bf16
#define OFF_QFB 8208      // 589824 bf16
#define OFF_QFA 303120    // 589824 bf16
#define OFF_QN  598032    // 36864 f32
#define OFF_XF  634896    // 589824 bf16
#define OFF_F2  929808    // 2359296 bf16
// total ~8.4 MB of d_ws

#define LOG2E 1.44269504f

typedef __attribute__((ext_vector_type(8))) short bf16x8;
typedef __attribute__((ext_vector_type(16))) float f32x16;
union U4 { uint4 u; bf16x8 b; };

__device__ __forceinline__ unsigned short f2bf(float x) {
    unsigned int u = __float_as_uint(x);
    unsigned int r = u + 0x7fffu + ((u >> 16) & 1u);
    return (unsigned short)(r >> 16);
}
__device__ __forceinline__ float bf2f(unsigned short v) {
    return __uint_as_float((unsigned int)v << 16);
}

// Fused prep: role by blockIdx. 0: bound; 1..64: A; 65..640: q; 641..928: xf.
__global__ __launch_bounds__(256) void k_prep(
    const float* __restrict__ x, const float* __restrict__ Wq,
    const float* __restrict__ bq, const float* __restrict__ Wv,
    const float* __restrict__ Wo, const float* __restrict__ gamma, float* ws)
{
    __shared__ __align__(16) char smem[8192];
    const int bid = blockIdx.x, t = threadIdx.x;

    if (bid == 0) {
        // ---- bound role ----
        double* red  = (double*)smem;          // 256 doubles
        double* sums = (double*)(smem + 2048); // 9 doubles
        for (int ph = 0; ph < 9; ++ph) {
            double s = 0.0;
            if (ph < 4) {
                const float* W = Wq + ph * 1024;
                for (int i = t; i < 1024; i += 256) { double v = W[i]; s += v * v; }
            } else if (ph < 8) {
                const float* W = Wv + (ph - 4) * 1024;
                for (int i = t; i < 1024; i += 256) { double v = W[i]; s += v * v; }
            } else {
                for (int i = t; i < 4096; i += 256) { double v = Wo[i]; s += v * v; }
            }
            red[t] = s; __syncthreads();
            for (int off = 128; off; off >>= 1) {
                if (t < off) red[t] += red[t + off];
                __syncthreads();
            }
            if (t == 0) sums[ph] = red[0];
            __syncthreads();
        }
        if (t == 0) {
            float z = 2304.0f / 2.7182818284590452f;
            float w = logf(z) - logf(logf(z));
            #pragma unroll 1
            for (int it = 0; it < 30; ++it) {
                float ew = __expf(w);
                w = w - (w * ew - z) / (ew * (w + 1.0f));
            }
            double phi = (double)w;
            double term = sqrt(sums[0]*sums[4] + sums[1]*sums[5] +
                               sums[2]*sums[6] + sums[3]*sums[7]);
            double bound = 6.0 * (4.0 * phi + 1.0) * term * sqrt(sums[8]);
            ws[OFF_SC] = (float)((double)gamma[0] / bound);
        }
    } else if (bid <= 64) {
        // ---- A role: A[h] = WqR@WqR^T/4 in bf16 frag layout ----
        float* WlP = (float*)smem;   // [64][17]
        int id = bid - 1, h = id >> 4, dq = id & 15;
        const float* W = Wq + h * 1024;
        for (int i = t; i < 1024; i += 256) WlP[(i >> 4) * 17 + (i & 15)] = W[i];
        __syncthreads();
        int dl = t >> 6, e = t & 63, d = dq * 4 + dl;
        float s = 0.f;
        #pragma unroll
        for (int k = 0; k < 16; ++k) s += WlP[d * 17 + k] * WlP[e * 17 + k];
        int tt = d >> 4, j = d & 7, l = ((d >> 3) & 1) * 32 + (e & 31), ec = e >> 5;
        unsigned short* af = (unsigned short*)(ws + OFF_AF);
        af[(((h * 4 + tt) * 2 + ec) * 64 + l) * 8 + j] = f2bf(0.25f * s);
    } else if (bid <= 640) {
        // ---- q role: thread = (n, k-quad). 576 blocks = 16 bh x 36 n-tiles ----
        float* WlT = (float*)smem;           // [64][16]
        float* bl  = (float*)(smem + 4096);  // 16
        float* qnp = (float*)(smem + 4160);  // [4][64]
        int rb = bid - 65, bh = rb / 36, nb = rb % 36;
        int h = bh & 3, b = bh >> 2;
        const float* W = Wq + h * 1024;
        for (int i = t; i < 1024; i += 256) WlT[(i & 63) * 16 + (i >> 6)] = W[i];
        if (t < 16) bl[t] = bq[h * 16 + t];
        __syncthreads();
        int nl = t & 63, kg = t >> 6, n = nb * 64 + nl;
        const float* xb = x + (size_t)b * 147456;
        const float4* wrow = (const float4*)WlT;   // [d][4 quads]
        float q0 = bl[kg*4], q1 = bl[kg*4+1], q2 = bl[kg*4+2], q3 = bl[kg*4+3];
        for (int d = 0; d < 64; ++d) {
            float xv = xb[d * 2304 + n];
            float4 wv = wrow[d * 4 + kg];
            q0 = fmaf(wv.x, xv, q0); q1 = fmaf(wv.y, xv, q1);
            q2 = fmaf(wv.z, xv, q2); q3 = fmaf(wv.w, xv, q3);
        }
        qnp[kg * 64 + nl] = q0*q0 + q1*q1 + q2*q2 + q3*q3;
        unsigned pB0 = (unsigned)f2bf(q0) | ((unsigned)f2bf(q1) << 16);
        unsigned pB1 = (unsigned)f2bf(q2) | ((unsigned)f2bf(q3) << 16);
        const float sA = 0.5f * LOG2E;
        unsigned pA0 = (unsigned)f2bf(sA*q0) | ((unsigned)f2bf(sA*q1) << 16);
        unsigned pA1 = (unsigned)f2bf(sA*q2) | ((unsigned)f2bf(sA*q3) << 16);
        // pair p = k/2: chunk = kg>>1, uint offset within chunk = (kg&1)*2
        size_t base = (size_t)(bh * 72 + (n >> 5)) * 256
                    + (size_t)(((kg >> 1) * 32 + (n & 31)) * 4 + (kg & 1) * 2);
        *(uint2*)((unsigned*)((unsigned short*)(ws + OFF_QFB)) + base) = make_uint2(pB0, pB1);
        *(uint2*)((unsigned*)((unsigned short*)(ws + OFF_QFA)) + base) = make_uint2(pA0, pA1);
        __syncthreads();
        if (t < 64) {
            float qn = qnp[t] + qnp[64 + t] + qnp[128 + t] + qnp[192 + t];
            ws[OFF_QN + bh * 2304 + nb * 64 + t] = -0.25f * LOG2E * qn;
        }
    } else {
        // ---- xf role: XF[b][T][dc][lane][j] frag transpose of x_r ----
        int i = (bid - 641) * 256 + t;
        int l = i & 63, c1 = i >> 6;
        int dc = c1 & 1, c2 = c1 >> 1;
        int T = c2 % 144, b = c2 / 144;
        const float* xb = x + (size_t)b * 147456;
        int col = dc * 32 + (l & 31), mbase = 16 * T + (l >> 5) * 8;
        unsigned int pk[4];
        #pragma unroll
        for (int jj = 0; jj < 4; ++jj) {
            float f0 = xb[(mbase + 2*jj) * 64 + col];
            float f1 = xb[(mbase + 2*jj + 1) * 64 + col];
            pk[jj] = (unsigned int)f2bf(f0) | ((unsigned int)f2bf(f1) << 16);
        }
        ((uint4*)((unsigned short*)(ws + OFF_XF)))[i] = make_uint4(pk[0], pk[1], pk[2], pk[3]);
    }
}

// One attention tile: C from LDS qn_s, QK MFMA, exp2, lrun sum, P->bf16, PV.
#define ATTN_TILE(XV, A0, A1, MT)                                               \
    {                                                                           \
        const int m0_ = (MT) * 64;                                              \
        f32x16 c0_, c1_;                                                        \
        _Pragma("unroll")                                                       \
        for (int g = 0; g < 4; ++g) {                                           \
            float4 t4_ = *(const float4*)(qn_s + m0_ + 8 * g + s4);             \
            c0_[4*g+0] = t4_.x + qoffl; c0_[4*g+1] = t4_.y + qoffl;             \
            c0_[4*g+2] = t4_.z + qoffl; c0_[4*g+3] = t4_.w + qoffl;             \
            float4 u4_ = *(const float4*)(qn_s + m0_ + 32 + 8 * g + s4);        \
            c1_[4*g+0] = u4_.x + qoffl; c1_[4*g+1] = u4_.y + qoffl;             \
            c1_[4*g+2] = u4_.z + qoffl; c1_[4*g+3] = u4_.w + qoffl;             \
        }                                                                       \
        f32x16 s0_ = __builtin_amdgcn_mfma_f32_32x32x16_bf16((A0).b, qb.b, c0_, 0, 0, 0); \
        f32x16 s1_ = __builtin_amdgcn_mfma_f32_32x32x16_bf16((A1).b, qb.b, c1_, 0, 0, 0); \
        float p_[32];                                                           \
        _Pragma("unroll")                                                       \
        for (int r = 0; r < 16; ++r)                                            \
            asm("v_exp_f32 %0, %1" : "=v"(p_[r]) : "v"(s0_[r]));                \
        _Pragma("unroll")                                                       \
        for (int r = 0; r < 16; ++r)                                            \
            asm("v_exp_f32 %0, %1" : "=v"(p_[16 + r]) : "v"(s1_[r]));           \
        float la_ = 0.f, lb_ = 0.f, lc_ = 0.f, ld_ = 0.f;                       \
        _Pragma("unroll")                                                       \
        for (int r = 0; r < 32; r += 4) {                                       \
            la_ += p_[r]; lb_ += p_[r+1]; lc_ += p_[r+2]; ld_ += p_[r+3];       \
        }                                                                       \
        lrun += (la_ + lb_) + (lc_ + ld_);                                      \
        _Pragma("unroll")                                                       \
        for (int c = 0; c < 2; ++c) {                                           \
            unsigned int wd_[8], xd_[8];                                        \
            _Pragma("unroll")                                                   \
            for (int i = 0; i < 8; ++i)                                         \
                asm("v_cvt_pk_bf16_f32 %0, %1, %2"                              \
                    : "=v"(wd_[i]) : "v"(p_[c*16 + 2*i]), "v"(p_[c*16 + 2*i + 1])); \
            _Pragma("unroll")                                                   \
            for (int i = 0; i < 8; ++i) xd_[i] = (unsigned int)__shfl_xor((int)wd_[i], 32); \
            U4 af0_, af1_;                                                      \
            af0_.u.x = hi ? xd_[2] : wd_[0];  af0_.u.y = hi ? xd_[3] : wd_[1];  \
            af0_.u.z = hi ? wd_[2] : xd_[0];  af0_.u.w = hi ? wd_[3] : xd_[1];  \
            af1_.u.x = hi ? xd_[6] : wd_[4];  af1_.u.y = hi ? xd_[7] : wd_[5];  \
            af1_.u.z = hi ? wd_[6] : xd_[4];  af1_.u.w = hi ? wd_[7] : xd_[5];  \
            O0 = __builtin_amdgcn_mfma_f32_32x32x16_bf16(af0_.b, (XV)[4*c+0].b, O0, 0, 0, 0); \
            O1 = __builtin_amdgcn_mfma_f32_32x32x16_bf16(af0_.b, (XV)[4*c+1].b, O1, 0, 0, 0); \
            O0 = __builtin_amdgcn_mfma_f32_32x32x16_bf16(af1_.b, (XV)[4*c+2].b, O0, 0, 0, 0); \
            O1 = __builtin_amdgcn_mfma_f32_32x32x16_bf16(af1_.b, (XV)[4*c+3].b, O1, 0, 0, 0); \
        }                                                                       \
    }

#define ATTN_LOAD(XV, A0, A1, MT)                                               \
    {                                                                           \
        _Pragma("unroll")                                                       \
        for (int q = 0; q < 8; ++q) (XV)[q].u = XF[(size_t)((MT) * 8 + q) * 64 + lane]; \
        (A0).u = QA[((MT) * 2) * 64 + lane];                                    \
        (A1).u = QA[((MT) * 2 + 1) * 64 + lane];                                \
    }

// Streaming (max-free) attention. Block = 4 waves = 32 q-rows; 4-way m-split,
// register ping-pong prefetch, qn staged in LDS (aliased by Ols after barrier).
__global__ __launch_bounds__(256, 2) void k_attn(float* __restrict__ ws)
{
    __shared__ __align__(16) char smem[40448];
    float* qn_s = (float*)smem;                          // [2304] phase 1
    float (*Ols)[32][68] = (float (*)[32][68])smem;      // [4][32][68] phase 2
    unsigned short (*fls)[80] = (unsigned short (*)[80])(smem + 34816);
    float* Lls = (float*)(smem + 34816 + 5120);          // [4][32]

    const int t = threadIdx.x, w = t >> 6, lane = t & 63;
    const int bid = blockIdx.x, bh = bid / 72, rc = bid % 72;
    const int h = bh & 3;
    const int b = bh >> 2;
    const int hi = lane >> 5, nl = lane & 31, s4 = hi * 4;

    const uint4* QB = (const uint4*)((const unsigned short*)(ws + OFF_QFB)) + (size_t)bh * 4608;
    const uint4* QA = (const uint4*)((const unsigned short*)(ws + OFF_QFA)) + (size_t)bh * 4608;
    const uint4* XF = (const uint4*)((const unsigned short*)(ws + OFF_XF)) + (size_t)b * 18432;
    const float* qn = ws + OFF_QN + bh * 2304;

    // stage qn into LDS (2304 f32 = 576 float4)
    for (int i = t; i < 576; i += 256)
        ((float4*)qn_s)[i] = ((const float4*)qn)[i];

    U4 qb; qb.u = QB[rc * 64 + lane];
    const float qoffl = qn[rc * 32 + nl];

    f32x16 O0, O1;
    #pragma unroll
    for (int i = 0; i < 16; ++i) { O0[i] = 0.f; O1[i] = 0.f; }
    float lrun = 0.f;

    U4 xvA[8], a0A, a1A, xvB[8], a0B, a1B;
    ATTN_LOAD(xvA, a0A, a1A, w);
    __syncthreads();   // qn_s ready

    #pragma unroll
    for (int it = 0; it < 9; ++it) {
        const int mt = w + it * 4;
        if (it & 1) {
            if (it < 8) ATTN_LOAD(xvA, a0A, a1A, mt + 4);
            ATTN_TILE(xvB, a0B, a1B, mt);
        } else {
            if (it < 8) ATTN_LOAD(xvB, a0B, a1B, mt + 4);
            ATTN_TILE(xvA, a0A, a1A, mt);
        }
    }
    __syncthreads();   // all waves done with qn_s before Ols aliases it

    // partial state -> LDS
    lrun += __shfl_xor(lrun, 32);
    #pragma unroll
    for (int r = 0; r < 16; ++r) {
        int n = (r & 3) + 8 * (r >> 2) + s4;
        Ols[w][n][nl]      = O0[r];
        Ols[w][n][nl + 32] = O1[r];
    }
    if (!hi) Lls[w * 32 + nl] = lrun;
    __syncthreads();

    // combine 4 partials, normalize, write f as bf16 tile
    {
        int n = t >> 3, d0 = (t & 7) * 8;
        float invL = 1.f / (Lls[n] + Lls[32 + n] + Lls[64 + n] + Lls[96 + n]);
        float f[8];
        #pragma unroll
        for (int j = 0; j < 8; ++j)
            f[j] = (Ols[0][n][d0+j] + Ols[1][n][d0+j] +
                    Ols[2][n][d0+j] + Ols[3][n][d0+j]) * invL;
        unsigned int pk[4];
        #pragma unroll
        for (int i = 0; i < 4; ++i)
            asm("v_cvt_pk_bf16_f32 %0, %1, %2" : "=v"(pk[i]) : "v"(f[2*i]), "v"(f[2*i+1]));
        *(uint4*)((char*)&fls[0][0] + n * 160 + d0 * 2) = make_uint4(pk[0], pk[1], pk[2], pk[3]);
    }
    __syncthreads();

    // f2 = f @ A : waves 0,1 handle e-columns ec*32..+31; store bf16
    if (w < 2) {
        const int ec = w;
        const uint4* AFp = (const uint4*)((const unsigned short*)(ws + OFF_AF)) + h * 512;
        f32x16 acc;
        #pragma unroll
        for (int i = 0; i < 16; ++i) acc[i] = 0.f;
        #pragma unroll
        for (int tt = 0; tt < 4; ++tt) {
            U4 a, bb;
            a.u  = *(const uint4*)((const char*)&fls[0][0] + nl * 160 + tt * 32 + hi * 16);
            bb.u = AFp[(tt * 2 + ec) * 64 + lane];
            acc = __builtin_amdgcn_mfma_f32_32x32x16_bf16(a.b, bb.b, acc, 0, 0, 0);
        }
        unsigned short* f2g = (unsigned short*)(ws + OFF_F2) +
                              (size_t)bh * 147456 + (size_t)rc * 32 * 64;
        #pragma unroll
        for (int r = 0; r < 16; ++r)
            f2g[((r & 3) + 8 * (r >> 2) + s4) * 64 + ec * 32 + nl] = f2bf(acc[r]);
    }
}

// Fused v+out: per target row n, the .view scatter collapses to
// k = n/144, np(c) = (n%144)*16 + c, col = h*16+c of the SAME row n.
// Block = 16 rows x (4h x 4cq | 16 o-quads). 576 blocks x 256.
__global__ __launch_bounds__(256) void k_post(
    const float* __restrict__ x, const float* __restrict__ Wv,
    const float* __restrict__ bv, const float* __restrict__ Wo,
    const float* __restrict__ bo, const float* __restrict__ ws,
    float* __restrict__ out)
{
    __shared__ float WvL[4096];      // [h][k][d]
    __shared__ float WoT[64 * 68];   // [d][o] pitch 68
    __shared__ float catL[16][68];
    __shared__ float bvL[64], boL[64];
    __shared__ float scs;
    const int bid = blockIdx.x, t = threadIdx.x;
    const int b = bid / 144, n0 = (bid % 144) * 16;
    for (int i = t; i < 4096; i += 256) WvL[i] = Wv[i];
    for (int i = t; i < 4096; i += 256) WoT[(i & 63) * 68 + (i >> 6)] = Wo[i];
    if (t < 64) { bvL[t] = bv[t]; boL[t] = bo[t]; }
    if (t == 0) scs = ws[OFF_SC];
    __syncthreads();

    const int nl = t & 15, q = t >> 4;
    const int n = n0 + nl;
    // ---- v phase: thread = (n, h, cq) ----
    {
        const int h = q >> 2, cq = q & 3;
        const int k = n / 144;
        const int np = (n % 144) * 16 + cq * 4;
        const unsigned short* f2p = (const unsigned short*)(ws + OFF_F2)
                                  + (size_t)(b * 4 + h) * 147456;
        const float* wv = WvL + h * 1024 + k * 64;
        float bvv = bvL[h * 16 + k];
        float v0 = bvv, v1 = bvv, v2 = bvv, v3 = bvv;
        for (int d = 0; d < 64; ++d) {
            ushort4 f4 = *(const ushort4*)(f2p + d * 2304 + np);
            float wd = wv[d];
            v0 = fmaf(wd, bf2f(f4.x), v0);
            v1 = fmaf(wd, bf2f(f4.y), v1);
            v2 = fmaf(wd, bf2f(f4.z), v2);
            v3 = fmaf(wd, bf2f(f4.w), v3);
        }
        int col = h * 16 + cq * 4;
        catL[nl][col + 0] = v0; catL[nl][col + 1] = v1;
        catL[nl][col + 2] = v2; catL[nl][col + 3] = v3;
    }
    __syncthreads();
    // ---- o phase: thread = (n, o-quad) ----
    {
        const int oq = q;
        const float4* wo4 = (const float4*)WoT;   // [d][17 float4]
        float a0 = boL[oq*4], a1 = boL[oq*4+1], a2 = boL[oq*4+2], a3 = boL[oq*4+3];
        for (int d = 0; d < 64; ++d) {
            float cv = catL[nl][d];
            float4 w4 = wo4[d * 17 + oq];
            a0 = fmaf(w4.x, cv, a0); a1 = fmaf(w4.y, cv, a1);
            a2 = fmaf(w4.z, cv, a2); a3 = fmaf(w4.w, cv, a3);
        }
        float sc = scs;
        const float* xb = x + (size_t)b * 147456;
        float* ob = out + (size_t)b * 147456;
        int o = oq * 4;
        ob[(o+0) * 2304 + n] = fmaf(sc, a0, xb[(o+0) * 2304 + n]);
        ob[(o+1) * 2304 + n] = fmaf(sc, a1, xb[(o+1) * 2304 + n]);
        ob[(o+2) * 2304 + n] = fmaf(sc, a2, xb[(o+2) * 2304 + n]);
        ob[(o+3) * 2304 + n] = fmaf(sc, a3, xb[(o+3) * 2304 + n]);
    }
}

extern "C" void kernel_launch(void* const* d_in, const int* in_sizes, int n_in,
                              void* d_out, int out_size, void* d_ws, size_t ws_size,
                              hipStream_t stream) {
    const float* x     = (const float*)d_in[0];
    const float* Wq    = (const float*)d_in[1];
    const float* bq    = (const float*)d_in[2];
    const float* Wv    = (const float*)d_in[3];
    const float* bv    = (const float*)d_in[4];
    const float* Wo    = (const float*)d_in[5];
    const float* bo    = (const float*)d_in[6];
    const float* gamma = (const float*)d_in[7];
    float* out = (float*)d_out;
    float* ws  = (float*)d_ws;
    k_prep<<<929,  256, 0, stream>>>(x, Wq, bq, Wv, Wo, gamma, ws);
    k_attn<<<1152, 256, 0, stream>>>(ws);
    k_post<<<576,  256, 0, stream>>>(x, Wv, bv, Wo, bo, ws, out);
}